// Round 3
// baseline (18641.348 us; speedup 1.0000x reference)
//
#include <hip/hip_runtime.h>
#include <math.h>

typedef _Float16 half8  __attribute__((ext_vector_type(8)));
typedef float    floatx4 __attribute__((ext_vector_type(4)));

#define MFMA16(a, b, c) __builtin_amdgcn_mfma_f32_16x16x32_f16((a), (b), (c), 0, 0, 0)

// ---------------- workspace layout (bytes) ----------------
constexpr unsigned WBIG_OFF = 0;          // f16 [736][224]  rows: 0..207 Wr, 208..415 Wz, 416..623 Wn, 624..735 dec_w1
constexpr unsigned W2_OFF   = 329728;     // f16 [64][128]   dec_w2^ (row=y2col, col=k)
constexpr unsigned WE1_OFF  = 346112;     // f16 [112][224]  enc_w1
constexpr unsigned WE2_OFF  = 396288;     // f16 [208][128]  enc_w2
constexpr unsigned WEL_OFF  = 449536;     // f16 [208][224]  enc_wl
constexpr unsigned WIHC_OFF = 542720;     // f32 [624]  w_ih column (gate-padded)
constexpr unsigned BSUM_OFF = 545216;     // f32 [624]  r,z: b_ih+b_hh ; n: b_ih
constexpr unsigned BHHN_OFF = 547712;     // f32 [208]  b_hh (n gate)
constexpr unsigned B1P_OFF  = 548544;     // f32 [112]
constexpr unsigned B2P_OFF  = 548992;     // f32 [64]
constexpr unsigned W3P_OFF  = 549248;     // f32 [64]
constexpr unsigned BE1_OFF  = 549504;     // f32 [112]
constexpr unsigned BE2_OFF  = 549952;     // f32 [208]
constexpr unsigned BEL_OFF  = 550784;     // f32 [208]
constexpr unsigned B3_OFF   = 551616;     // f32 [1] (+pad)
constexpr unsigned CT_OFF   = 551632;     // f64 [100][2] twiddles (cos,sin)/100, exact zeros forced
constexpr unsigned WS_NEED  = 553232;

// ---------------- LDS layout (bytes) ----------------
// decoder:  Hb f16 [128][212] @0 (54272) | Y1 f16 [128][104] @54272 (26624) | DECIN f32[128] @80896 (512)
// encoder (per 64-row sub): XF f32[64][101] / X1 f16[64][104] @ sub*27136 (inside Hb half)
//           SIG/X2 f16 [64][208] @54272 (Y1 region); CT f64 pairs hidden in SIG cols 0..99 byte area
constexpr unsigned Y1_OFF    = 54272;
constexpr unsigned DECIN_OFF = 80896;
constexpr unsigned SMEM_BYTES = 81408;   // 2 blocks/CU (162816 <= 163840)

__device__ __forceinline__ half8 lds_frag(const _Float16* p) {
  // 16B at 8B alignment (Hb stride 212 f16 = 424B) -> two ds_read_b64
  union { uint2 u[2]; half8 h; } cv;
  cv.u[0] = *(const uint2*)p;
  cv.u[1] = *(const uint2*)(p + 4);
  return cv.h;
}
__device__ __forceinline__ half8 lds_frag16(const _Float16* p) {
  // 16B-aligned rows (stride 104/208 f16) -> ds_read_b128
  union { uint4 u; half8 h; } cv;
  cv.u = *(const uint4*)p;
  return cv.h;
}
__device__ __forceinline__ half8 g_frag(const _Float16* p) {
  union { uint4 u; half8 h; } cv;
  cv.u = *(const uint4*)p;      // global_load_dwordx4
  return cv.h;
}
__device__ __forceinline__ float sigm(float x) {
  return __builtin_amdgcn_rcpf(1.f + __builtin_amdgcn_exp2f(-1.44269504f * x));
}
__device__ __forceinline__ float tanh_(float x) {
  return 1.f - 2.f * __builtin_amdgcn_rcpf(1.f + __builtin_amdgcn_exp2f(2.88539008f * x));
}
__device__ __forceinline__ unsigned pack2(float a, float b) {
  union { _Float16 h[2]; unsigned u; } x;
  x.h[0] = (_Float16)a; x.h[1] = (_Float16)b; return x.u;
}
__device__ __forceinline__ _Float16 unpk(unsigned u, int hi) {
  union { unsigned u; _Float16 h[2]; } x; x.u = u; return x.h[hi];
}

// =================== prep: pack weights to fp16, build twiddles ===================
__global__ __launch_bounds__(256) void prep_kernel(
    const float* __restrict__ enc_w1, const float* __restrict__ enc_b1,
    const float* __restrict__ enc_w2, const float* __restrict__ enc_b2,
    const float* __restrict__ enc_wl, const float* __restrict__ enc_bl,
    const float* __restrict__ w_ih,  const float* __restrict__ w_hh,
    const float* __restrict__ b_ih,  const float* __restrict__ b_hh,
    const float* __restrict__ dw1, const float* __restrict__ db1,
    const float* __restrict__ dw2, const float* __restrict__ db2,
    const float* __restrict__ dw3, const float* __restrict__ db3,
    unsigned char* __restrict__ ws)
{
  const int g = blockIdx.x * blockDim.x + threadIdx.x;
  const int st = gridDim.x * blockDim.x;
  _Float16* Wbig = (_Float16*)(ws + WBIG_OFF);
  for (int i = g; i < 736 * 224; i += st) {
    int row = i / 224, k = i - row * 224;
    float v = 0.f;
    if (k < 200) {
      if (row < 624) { int gg = row / 208, j = row - gg * 208;
        if (j < 200) v = w_hh[(gg * 200 + j) * 200 + k]; }
      else { int j = row - 624; if (j < 100) v = dw1[j * 200 + k]; }
    }
    Wbig[i] = (_Float16)v;
  }
  _Float16* W2 = (_Float16*)(ws + W2_OFF);
  for (int i = g; i < 64 * 128; i += st) {
    int r = i / 128, k = i - r * 128;
    W2[i] = (_Float16)((r < 50 && k < 100) ? dw2[r * 100 + k] : 0.f);
  }
  _Float16* We1 = (_Float16*)(ws + WE1_OFF);
  for (int i = g; i < 112 * 224; i += st) {
    int r = i / 224, k = i - r * 224;
    We1[i] = (_Float16)((r < 100 && k < 202) ? enc_w1[r * 202 + k] : 0.f);
  }
  _Float16* We2 = (_Float16*)(ws + WE2_OFF);
  for (int i = g; i < 208 * 128; i += st) {
    int r = i / 128, k = i - r * 128;
    We2[i] = (_Float16)((r < 202 && k < 100) ? enc_w2[r * 100 + k] : 0.f);
  }
  _Float16* Wel = (_Float16*)(ws + WEL_OFF);
  for (int i = g; i < 208 * 224; i += st) {
    int r = i / 224, k = i - r * 224;
    Wel[i] = (_Float16)((r < 200 && k < 202) ? enc_wl[r * 202 + k] : 0.f);
  }
  float* wihc = (float*)(ws + WIHC_OFF);
  float* bsum = (float*)(ws + BSUM_OFF);
  for (int i = g; i < 624; i += st) {
    int gg = i / 208, j = i - gg * 208;
    wihc[i] = (j < 200) ? w_ih[gg * 200 + j] : 0.f;
    float b = 0.f;
    if (j < 200) b = (gg < 2) ? (b_ih[gg * 200 + j] + b_hh[gg * 200 + j]) : b_ih[400 + j];
    bsum[i] = b;
  }
  float* bhhn = (float*)(ws + BHHN_OFF);
  for (int i = g; i < 208; i += st) bhhn[i] = (i < 200) ? b_hh[400 + i] : 0.f;
  float* b1p = (float*)(ws + B1P_OFF);
  for (int i = g; i < 112; i += st) b1p[i] = (i < 100) ? db1[i] : 0.f;
  float* b2p = (float*)(ws + B2P_OFF);
  for (int i = g; i < 64; i += st) b2p[i] = (i < 50) ? db2[i] : 0.f;
  float* w3p = (float*)(ws + W3P_OFF);
  for (int i = g; i < 64; i += st) w3p[i] = (i < 50) ? dw3[i] : 0.f;
  float* be1 = (float*)(ws + BE1_OFF);
  for (int i = g; i < 112; i += st) be1[i] = (i < 100) ? enc_b1[i] : 0.f;
  float* be2 = (float*)(ws + BE2_OFF);
  for (int i = g; i < 208; i += st) be2[i] = (i < 202) ? enc_b2[i] : 0.f;
  float* bel = (float*)(ws + BEL_OFF);
  for (int i = g; i < 208; i += st) bel[i] = (i < 200) ? enc_bl[i] : 0.f;
  if (g == 0) *(float*)(ws + B3_OFF) = db3[0];
  double* ct = (double*)(ws + CT_OFF);
  for (int m = g; m < 100; m += st) {
    double c, s;
    if      (m == 0)  { c = 1.0;  s = 0.0; }
    else if (m == 25) { c = 0.0;  s = -1.0; }
    else if (m == 50) { c = -1.0; s = 0.0; }
    else if (m == 75) { c = 0.0;  s = 1.0; }
    else { double a = -2.0 * 3.14159265358979323846 * (double)m / 100.0; c = cos(a); s = sin(a); }
    ct[2 * m]     = c * 0.01;   // forward norm 1/100 folded in
    ct[2 * m + 1] = s * 0.01;
  }
}

// =================== fused encoder + 50-step GRU decoder ===================
// 128 rows/block, 512 thr (8 waves). wave = (rg: row-half of 64) x (cg: col-quarter).
// 2 blocks/CU (LDS 81,408 x2). All per-thread arrays statically indexed (no scratch).
__global__ __launch_bounds__(512, 4) void fused_kernel(
    const float* __restrict__ enc_in, const unsigned char* __restrict__ ws,
    float* __restrict__ out)
{
  __shared__ __align__(16) unsigned char smem[SMEM_BYTES];
  _Float16* Hb    = (_Float16*)smem;                   // [128][212]
  _Float16* Y1    = (_Float16*)(smem + Y1_OFF);        // [128][104]
  float*    DECIN = (float*)(smem + DECIN_OFF);        // [128]

  const _Float16* Wbig = (const _Float16*)(ws + WBIG_OFF);
  const _Float16* W2w  = (const _Float16*)(ws + W2_OFF);
  const _Float16* We1  = (const _Float16*)(ws + WE1_OFF);
  const _Float16* We2  = (const _Float16*)(ws + WE2_OFF);
  const _Float16* Wel  = (const _Float16*)(ws + WEL_OFF);
  const float* wihc = (const float*)(ws + WIHC_OFF);
  const float* bsum = (const float*)(ws + BSUM_OFF);
  const float* bhhn = (const float*)(ws + BHHN_OFF);
  const float* b1p  = (const float*)(ws + B1P_OFF);
  const float* b2p  = (const float*)(ws + B2P_OFF);
  const float* w3p  = (const float*)(ws + W3P_OFF);
  const float* be1  = (const float*)(ws + BE1_OFF);
  const float* be2  = (const float*)(ws + BE2_OFF);
  const float* bel  = (const float*)(ws + BEL_OFF);
  const float b3v   = *(const float*)(ws + B3_OFF);

  const int tid = threadIdx.x;
  const int lane = tid & 63, wv = tid >> 6;
  const int q = lane >> 4, c = lane & 15;
  const int rg = wv >> 2, cg = wv & 3;
  const int row0 = blockIdx.x * 128;
  const half8 Z8 = {};

  // ---------------- ENCODER: 2 sub-rounds of 64 rows ----------------
#pragma unroll 1
  for (int sub = 0; sub < 2; ++sub) {
    float*    XF   = (float*)(smem + sub * 27136);        // [64][101] inside Hb half
    _Float16* X1   = (_Float16*)(smem + sub * 27136);     // [64][104] (after DFT)
    _Float16* SIGX = (_Float16*)(smem + Y1_OFF);          // [64][208] (Y1 region); X2 overlays
    __syncthreads();
    for (int i = tid; i < 6400; i += 512) {
      int r = i / 100, t = i - r * 100;
      XF[r * 101 + t] = enc_in[(size_t)(row0 + sub * 64 + r) * 100 + t];
    }
    {
      const double* ctg = (const double*)(ws + CT_OFF);
      for (int i = tid; i < 100; i += 512) {
        double* d = (double*)(smem + Y1_OFF + ((i >> 3) * 416 + (i & 7) * 16));
        d[0] = ctg[2 * i]; d[1] = ctg[2 * i + 1];
      }
    }
    __syncthreads();
    // --- fp64 DFT (sign-safe angles); lane = row, wave-uniform bin ---
    for (int kb = wv; kb < 51; kb += 8) {
      double re = 0.0, im = 0.0; int m = 0;
      const float* xr = XF + lane * 101;
      for (int t = 0; t < 100; ++t) {
        const double* cp = (const double*)(smem + Y1_OFF + ((m >> 3) * 416 + (m & 7) * 16));
        double x = (double)xr[t];
        re = fma(x, cp[0], re);
        im = fma(x, cp[1], im);
        m += kb; if (m >= 100) m -= 100;
      }
      if (kb == 0 || kb == 50) im = 0.0;             // match pocketfft exact-real DC/Nyquist
      float ab = (float)sqrt(re * re + im * im);
      float an = atan2f((float)im, (float)re);
      SIGX[lane * 208 + 100 + kb] = (_Float16)ab;
      SIGX[lane * 208 + 151 + kb] = (_Float16)an;
    }
    __syncthreads();
    // time-domain cols + K-pad zeros (CT dead now)
    for (int i = tid; i < 6400; i += 512) {
      int r = i / 100, t = i - r * 100;
      SIGX[r * 208 + t] = (_Float16)XF[r * 101 + t];
    }
    for (int i = tid; i < 64 * 6; i += 512) {
      int r = i / 6; SIGX[r * 208 + 202 + (i - r * 6)] = (_Float16)0.f;
    }
    __syncthreads();
    // --- enc1: sig(K208) -> x1 ---
#pragma unroll 1
    for (int jt = wv; jt < 7; jt += 8) {
      floatx4 C[4] = {{0,0,0,0},{0,0,0,0},{0,0,0,0},{0,0,0,0}};
      const _Float16* wp = We1 + (jt * 16 + c) * 224 + q * 8;
#pragma unroll
      for (int s = 0; s < 7; ++s) {
        half8 B = g_frag(wp + s * 32);
#pragma unroll
        for (int m = 0; m < 4; ++m) {
          half8 Af = (s == 6 && q >= 2) ? Z8 : lds_frag16(SIGX + (m * 16 + c) * 208 + q * 8 + s * 32);
          C[m] = MFMA16(Af, B, C[m]);
        }
      }
      int col = jt * 16 + c; float bv = be1[col]; bool wm = col < 104;
#pragma unroll
      for (int m = 0; m < 4; ++m)
#pragma unroll
        for (int r = 0; r < 4; ++r) {
          float v = C[m][r] + bv; v = fmaxf(v, 0.01f * v);
          if (wm) X1[(m * 16 + 4 * q + r) * 104 + col] = (_Float16)v;
        }
    }
    __syncthreads();
    // --- enc2: x1(K104) -> x2 (overlays SIG region) ---
#pragma unroll 1
    for (int jt = wv; jt < 13; jt += 8) {
      floatx4 C[4] = {{0,0,0,0},{0,0,0,0},{0,0,0,0},{0,0,0,0}};
      const _Float16* wp = We2 + (jt * 16 + c) * 128 + q * 8;
#pragma unroll
      for (int s = 0; s < 4; ++s) {
        half8 B = g_frag(wp + s * 32);
#pragma unroll
        for (int m = 0; m < 4; ++m) {
          half8 Af = (s == 3 && q >= 1) ? Z8 : lds_frag16(X1 + (m * 16 + c) * 104 + q * 8 + s * 32);
          C[m] = MFMA16(Af, B, C[m]);
        }
      }
      int col = jt * 16 + c; float bv = be2[col];
#pragma unroll
      for (int m = 0; m < 4; ++m)
#pragma unroll
        for (int r = 0; r < 4; ++r) {
          float v = C[m][r] + bv; v = fmaxf(v, 0.01f * v);
          SIGX[(m * 16 + 4 * q + r) * 208 + col] = (_Float16)v;   // X2
        }
    }
    __syncthreads();
    // --- encl: x2(K208) -> h0 rows ---
#pragma unroll 1
    for (int jt = wv; jt < 13; jt += 8) {
      floatx4 C[4] = {{0,0,0,0},{0,0,0,0},{0,0,0,0},{0,0,0,0}};
      const _Float16* wp = Wel + (jt * 16 + c) * 224 + q * 8;
#pragma unroll
      for (int s = 0; s < 7; ++s) {
        half8 B = g_frag(wp + s * 32);
#pragma unroll
        for (int m = 0; m < 4; ++m) {
          half8 Af = (s == 6 && q >= 2) ? Z8 : lds_frag16(SIGX + (m * 16 + c) * 208 + q * 8 + s * 32);
          C[m] = MFMA16(Af, B, C[m]);
        }
      }
      int col = jt * 16 + c; float bv = bel[col]; bool wm = col < 200;
#pragma unroll
      for (int m = 0; m < 4; ++m)
#pragma unroll
        for (int r = 0; r < 4; ++r) {
          float v = C[m][r] + bv;
          if (wm) Hb[(sub * 64 + m * 16 + 4 * q + r) * 212 + col] = (_Float16)v;
        }
    }
  }
  __syncthreads();
  // zero Hb K-pad cols 200..211 (scratch overwrote them) + dec_in0
  for (int i = tid; i < 128 * 12; i += 512) {
    int r = i / 12; Hb[r * 212 + 200 + (i - r * 12)] = (_Float16)0.f;
  }
  for (int i = tid; i < 128; i += 512)
    DECIN[i] = enc_in[(size_t)(row0 + i) * 100 + 99];
  __syncthreads();

  // ---------------- DECODER: 51 iterations, 4 barriers each ----------------
#pragma unroll 1
  for (int k = 0; k <= 50; ++k) {
    if (k >= 1) {
      // ---- phase A: y1 = lrelu(h_k @ dec_w1^T + b1); wave (rg,cg): rows rg*64.., jt = cg, cg+4 ----
#pragma unroll
      for (int ji = 0; ji < 2; ++ji) {
        int jt = cg + ji * 4;
        if (jt < 7) {
          floatx4 C[4] = {{0,0,0,0},{0,0,0,0},{0,0,0,0},{0,0,0,0}};
          const _Float16* wp = Wbig + (624 + jt * 16 + c) * 224 + q * 8;
#pragma unroll
          for (int s = 0; s < 7; ++s) {
            half8 B = g_frag(wp + s * 32);
#pragma unroll
            for (int m = 0; m < 4; ++m) {
              half8 Af = (s == 6 && q >= 2) ? Z8 : lds_frag(Hb + (rg * 64 + m * 16 + c) * 212 + q * 8 + s * 32);
              C[m] = MFMA16(Af, B, C[m]);
            }
          }
          int col = jt * 16 + c; float bv = b1p[col]; bool wm = col < 104;
#pragma unroll
          for (int m = 0; m < 4; ++m)
#pragma unroll
            for (int r = 0; r < 4; ++r) {
              float v = C[m][r] + bv; v = fmaxf(v, 0.01f * v);
              if (wm) Y1[(rg * 64 + m * 16 + 4 * q + r) * 104 + col] = (_Float16)v;
            }
        }
      }
      __syncthreads();
      // ---- phase B (waves 0,1 only): y2 -> y3 -> y_{k-1}; wave wv: rows wv*64..+63 ----
      if (wv < 2) {
        float ya[4][4] = {{0,0,0,0},{0,0,0,0},{0,0,0,0},{0,0,0,0}};
#pragma unroll 1
        for (int jt = 0; jt < 4; ++jt) {
          half8 Bw[4];
          const _Float16* wp = W2w + (jt * 16 + c) * 128 + q * 8;
#pragma unroll
          for (int s = 0; s < 4; ++s) Bw[s] = g_frag(wp + s * 32);
          int col = jt * 16 + c; float b2v = b2p[col], w3v = w3p[col];
#pragma unroll
          for (int m = 0; m < 4; ++m) {
            floatx4 Cy = {0.f, 0.f, 0.f, 0.f};
#pragma unroll
            for (int s = 0; s < 4; ++s) {
              half8 A2 = (s == 3 && q >= 1) ? Z8 : lds_frag16(Y1 + (wv * 64 + m * 16 + c) * 104 + q * 8 + s * 32);
              Cy = MFMA16(A2, Bw[s], Cy);
            }
#pragma unroll
            for (int r = 0; r < 4; ++r) {
              float v = Cy[r] + b2v; v = fmaxf(v, 0.01f * v);
              ya[m][r] = fmaf(v, w3v, ya[m][r]);
            }
          }
        }
#pragma unroll
        for (int m = 0; m < 4; ++m)
#pragma unroll
          for (int r = 0; r < 4; ++r) {
            float v = ya[m][r];
            v += __shfl_xor(v, 1); v += __shfl_xor(v, 2);
            v += __shfl_xor(v, 4); v += __shfl_xor(v, 8);
            if (c == 0) {
              int rowL = wv * 64 + m * 16 + 4 * q + r;
              float y = v + b3v;
              DECIN[rowL] = y;
              out[(size_t)(row0 + rowL) * 50 + (k - 1)] = y;
            }
          }
      }
      __syncthreads();
    }
    if (k <= 49) {
      // ---- phase C: 3-gate GEMM + GRU update; h_new carried in statically-indexed regs ----
      unsigned hn4[4][4][2];   // [ji][m][pair] — ji/m/pair all static (full unroll)
#pragma unroll
      for (int ji = 0; ji < 4; ++ji) {
        int jt = cg + ji * 4;
        if (jt < 13) {
          const _Float16* wp = Wbig + (jt * 16 + c) * 224 + q * 8;
          floatx4 Cr[4] = {{0,0,0,0},{0,0,0,0},{0,0,0,0},{0,0,0,0}};
          floatx4 Cz[4] = {{0,0,0,0},{0,0,0,0},{0,0,0,0},{0,0,0,0}};
          floatx4 Cn[4] = {{0,0,0,0},{0,0,0,0},{0,0,0,0},{0,0,0,0}};
#pragma unroll
          for (int s = 0; s < 7; ++s) {
            half8 Br = g_frag(wp + s * 32);
            half8 Bz = g_frag(wp + 208 * 224 + s * 32);
            half8 Bn = g_frag(wp + 416 * 224 + s * 32);
#pragma unroll
            for (int m = 0; m < 4; ++m) {
              half8 Af = (s == 6 && q >= 2) ? Z8 : lds_frag(Hb + (rg * 64 + m * 16 + c) * 212 + q * 8 + s * 32);
              Cr[m] = MFMA16(Af, Br, Cr[m]);
              Cz[m] = MFMA16(Af, Bz, Cz[m]);
              Cn[m] = MFMA16(Af, Bn, Cn[m]);
            }
          }
          int col = jt * 16 + c;
          float wr = wihc[col], wz = wihc[208 + col], wn = wihc[416 + col];
          float br = bsum[col], bz = bsum[208 + col], bnih = bsum[416 + col];
          float bnhh = bhhn[col];
#pragma unroll
          for (int m = 0; m < 4; ++m) {
            int rbase = (rg * 64 + m * 16 + 4 * q) * 212 + col;
            float hv[4];
#pragma unroll
            for (int r = 0; r < 4; ++r) {
              float d = DECIN[rg * 64 + m * 16 + 4 * q + r];
              float rgate = sigm(Cr[m][r] + fmaf(d, wr, br));
              float zgate = sigm(Cz[m][r] + fmaf(d, wz, bz));
              float ngate = tanh_(fmaf(d, wn, bnih) + rgate * (Cn[m][r] + bnhh));
              float ho = (float)Hb[rbase + r * 212];
              hv[r] = fmaf(zgate, ho - ngate, ngate);
            }
            hn4[ji][m][0] = pack2(hv[0], hv[1]);
            hn4[ji][m][1] = pack2(hv[2], hv[3]);
          }
        }
      }
      __syncthreads();   // all reads of h_k complete before any h_{k+1} write
#pragma unroll
      for (int ji = 0; ji < 4; ++ji) {
        int jt = cg + ji * 4;
        int col = jt * 16 + c;
        bool wm = (jt < 13) && (col < 200);
#pragma unroll
        for (int m = 0; m < 4; ++m)
#pragma unroll
          for (int rr = 0; rr < 2; ++rr) {
            unsigned u = hn4[ji][m][rr];
            int row = rg * 64 + m * 16 + 4 * q + rr * 2;
            if (wm) {
              Hb[row * 212 + col]       = unpk(u, 0);
              Hb[(row + 1) * 212 + col] = unpk(u, 1);
            }
          }
      }
    }
    __syncthreads();
  }
}

extern "C" void kernel_launch(void* const* d_in, const int* in_sizes, int n_in,
                              void* d_out, int out_size, void* d_ws, size_t ws_size,
                              hipStream_t stream) {
  const float* enc_in = (const float*)d_in[0];
  const float* enc_w1 = (const float*)d_in[1];
  const float* enc_b1 = (const float*)d_in[2];
  const float* enc_w2 = (const float*)d_in[3];
  const float* enc_b2 = (const float*)d_in[4];
  const float* enc_wl = (const float*)d_in[5];
  const float* enc_bl = (const float*)d_in[6];
  const float* w_ih   = (const float*)d_in[7];
  const float* w_hh   = (const float*)d_in[8];
  const float* b_ih   = (const float*)d_in[9];
  const float* b_hh   = (const float*)d_in[10];
  const float* dw1    = (const float*)d_in[11];
  const float* db1    = (const float*)d_in[12];
  const float* dw2    = (const float*)d_in[13];
  const float* db2    = (const float*)d_in[14];
  const float* dw3    = (const float*)d_in[15];
  const float* db3    = (const float*)d_in[16];
  unsigned char* ws = (unsigned char*)d_ws;
  float* out = (float*)d_out;

  prep_kernel<<<dim3(256), dim3(256), 0, stream>>>(
      enc_w1, enc_b1, enc_w2, enc_b2, enc_wl, enc_bl,
      w_ih, w_hh, b_ih, b_hh, dw1, db1, dw2, db2, dw3, db3, ws);
  fused_kernel<<<dim3(1024), dim3(512), 0, stream>>>(enc_in, ws, out);
}

// Round 4
// 15210.394 us; speedup vs baseline: 1.2256x; 1.2256x over previous
//
#include <hip/hip_runtime.h>
#include <math.h>

typedef _Float16 half8  __attribute__((ext_vector_type(8)));
typedef float    floatx4 __attribute__((ext_vector_type(4)));

#define MFMA16(a, b, c) __builtin_amdgcn_mfma_f32_16x16x32_f16((a), (b), (c), 0, 0, 0)

// ---------------- workspace layout (bytes) ----------------
constexpr unsigned WBIG_OFF = 0;          // f16 [736][224]  rows: 0..207 Wr, 208..415 Wz, 416..623 Wn, 624..735 dec_w1
constexpr unsigned W2_OFF   = 329728;     // f16 [64][128]   dec_w2^ (row=y2col, col=k)
constexpr unsigned WE1_OFF  = 346112;     // f16 [112][224]  enc_w1
constexpr unsigned WE2_OFF  = 396288;     // f16 [208][128]  enc_w2
constexpr unsigned WEL_OFF  = 449536;     // f16 [208][224]  enc_wl
constexpr unsigned WIHC_OFF = 542720;     // f32 [624]  w_ih column (gate-padded)
constexpr unsigned BSUM_OFF = 545216;     // f32 [624]  r,z: b_ih+b_hh ; n: b_ih
constexpr unsigned BHHN_OFF = 547712;     // f32 [208]  b_hh (n gate)
constexpr unsigned B1P_OFF  = 548544;     // f32 [112]
constexpr unsigned B2P_OFF  = 548992;     // f32 [64]
constexpr unsigned W3P_OFF  = 549248;     // f32 [64]
constexpr unsigned BE1_OFF  = 549504;     // f32 [112]
constexpr unsigned BE2_OFF  = 549952;     // f32 [208]
constexpr unsigned BEL_OFF  = 550784;     // f32 [208]
constexpr unsigned B3_OFF   = 551616;     // f32 [1] (+pad)
constexpr unsigned CT_OFF   = 551632;     // f64 [100][2] twiddles (cos,sin)/100, exact zeros forced
constexpr unsigned WS_NEED  = 553232;

// ---------------- LDS layout (bytes) ----------------
// decoder:  Hb f16 [128][212] @0 (54272) | Y1 f16 [128][104] @54272 (26624) | DECIN f32[128] @80896 (512)
// encoder (per 64-row sub): XF f32[64][101] / X1 f16[64][104] @ sub*27136 (inside Hb half)
//           SIG/X2 f16 [64][208] @54272 (Y1 region); CT f64 pairs hidden in SIG cols 0..99 byte area
constexpr unsigned Y1_OFF    = 54272;
constexpr unsigned DECIN_OFF = 80896;
constexpr unsigned SMEM_BYTES = 81408;   // 2 blocks/CU (162816 <= 163840)

__device__ __forceinline__ half8 lds_frag(const _Float16* p) {
  // 16B at 8B alignment (Hb stride 212 f16 = 424B) -> two ds_read_b64
  union { uint2 u[2]; half8 h; } cv;
  cv.u[0] = *(const uint2*)p;
  cv.u[1] = *(const uint2*)(p + 4);
  return cv.h;
}
__device__ __forceinline__ half8 lds_frag16(const _Float16* p) {
  // 16B-aligned rows (stride 104/208 f16) -> ds_read_b128
  union { uint4 u; half8 h; } cv;
  cv.u = *(const uint4*)p;
  return cv.h;
}
__device__ __forceinline__ half8 g_frag(const _Float16* p) {
  union { uint4 u; half8 h; } cv;
  cv.u = *(const uint4*)p;      // global_load_dwordx4
  return cv.h;
}
__device__ __forceinline__ float sigm(float x) {
  return __builtin_amdgcn_rcpf(1.f + __builtin_amdgcn_exp2f(-1.44269504f * x));
}
__device__ __forceinline__ float tanh_(float x) {
  return 1.f - 2.f * __builtin_amdgcn_rcpf(1.f + __builtin_amdgcn_exp2f(2.88539008f * x));
}
__device__ __forceinline__ unsigned pack2(float a, float b) {
  union { _Float16 h[2]; unsigned u; } x;
  x.h[0] = (_Float16)a; x.h[1] = (_Float16)b; return x.u;
}
__device__ __forceinline__ _Float16 unpk(unsigned u, int hi) {
  union { unsigned u; _Float16 h[2]; } x; x.u = u; return x.h[hi];
}

// =================== prep: pack weights to fp16, build twiddles ===================
__global__ __launch_bounds__(256) void prep_kernel(
    const float* __restrict__ enc_w1, const float* __restrict__ enc_b1,
    const float* __restrict__ enc_w2, const float* __restrict__ enc_b2,
    const float* __restrict__ enc_wl, const float* __restrict__ enc_bl,
    const float* __restrict__ w_ih,  const float* __restrict__ w_hh,
    const float* __restrict__ b_ih,  const float* __restrict__ b_hh,
    const float* __restrict__ dw1, const float* __restrict__ db1,
    const float* __restrict__ dw2, const float* __restrict__ db2,
    const float* __restrict__ dw3, const float* __restrict__ db3,
    unsigned char* __restrict__ ws)
{
  const int g = blockIdx.x * blockDim.x + threadIdx.x;
  const int st = gridDim.x * blockDim.x;
  _Float16* Wbig = (_Float16*)(ws + WBIG_OFF);
  for (int i = g; i < 736 * 224; i += st) {
    int row = i / 224, k = i - row * 224;
    float v = 0.f;
    if (k < 200) {
      if (row < 624) { int gg = row / 208, j = row - gg * 208;
        if (j < 200) v = w_hh[(gg * 200 + j) * 200 + k]; }
      else { int j = row - 624; if (j < 100) v = dw1[j * 200 + k]; }
    }
    Wbig[i] = (_Float16)v;
  }
  _Float16* W2 = (_Float16*)(ws + W2_OFF);
  for (int i = g; i < 64 * 128; i += st) {
    int r = i / 128, k = i - r * 128;
    W2[i] = (_Float16)((r < 50 && k < 100) ? dw2[r * 100 + k] : 0.f);
  }
  _Float16* We1 = (_Float16*)(ws + WE1_OFF);
  for (int i = g; i < 112 * 224; i += st) {
    int r = i / 224, k = i - r * 224;
    We1[i] = (_Float16)((r < 100 && k < 202) ? enc_w1[r * 202 + k] : 0.f);
  }
  _Float16* We2 = (_Float16*)(ws + WE2_OFF);
  for (int i = g; i < 208 * 128; i += st) {
    int r = i / 128, k = i - r * 128;
    We2[i] = (_Float16)((r < 202 && k < 100) ? enc_w2[r * 100 + k] : 0.f);
  }
  _Float16* Wel = (_Float16*)(ws + WEL_OFF);
  for (int i = g; i < 208 * 224; i += st) {
    int r = i / 224, k = i - r * 224;
    Wel[i] = (_Float16)((r < 200 && k < 202) ? enc_wl[r * 202 + k] : 0.f);
  }
  float* wihc = (float*)(ws + WIHC_OFF);
  float* bsum = (float*)(ws + BSUM_OFF);
  for (int i = g; i < 624; i += st) {
    int gg = i / 208, j = i - gg * 208;
    wihc[i] = (j < 200) ? w_ih[gg * 200 + j] : 0.f;
    float b = 0.f;
    if (j < 200) b = (gg < 2) ? (b_ih[gg * 200 + j] + b_hh[gg * 200 + j]) : b_ih[400 + j];
    bsum[i] = b;
  }
  float* bhhn = (float*)(ws + BHHN_OFF);
  for (int i = g; i < 208; i += st) bhhn[i] = (i < 200) ? b_hh[400 + i] : 0.f;
  float* b1p = (float*)(ws + B1P_OFF);
  for (int i = g; i < 112; i += st) b1p[i] = (i < 100) ? db1[i] : 0.f;
  float* b2p = (float*)(ws + B2P_OFF);
  for (int i = g; i < 64; i += st) b2p[i] = (i < 50) ? db2[i] : 0.f;
  float* w3p = (float*)(ws + W3P_OFF);
  for (int i = g; i < 64; i += st) w3p[i] = (i < 50) ? dw3[i] : 0.f;
  float* be1 = (float*)(ws + BE1_OFF);
  for (int i = g; i < 112; i += st) be1[i] = (i < 100) ? enc_b1[i] : 0.f;
  float* be2 = (float*)(ws + BE2_OFF);
  for (int i = g; i < 208; i += st) be2[i] = (i < 202) ? enc_b2[i] : 0.f;
  float* bel = (float*)(ws + BEL_OFF);
  for (int i = g; i < 208; i += st) bel[i] = (i < 200) ? enc_bl[i] : 0.f;
  if (g == 0) *(float*)(ws + B3_OFF) = db3[0];
  double* ct = (double*)(ws + CT_OFF);
  for (int m = g; m < 100; m += st) {
    double c, s;
    if      (m == 0)  { c = 1.0;  s = 0.0; }
    else if (m == 25) { c = 0.0;  s = -1.0; }
    else if (m == 50) { c = -1.0; s = 0.0; }
    else if (m == 75) { c = 0.0;  s = 1.0; }
    else { double a = -2.0 * 3.14159265358979323846 * (double)m / 100.0; c = cos(a); s = sin(a); }
    ct[2 * m]     = c * 0.01;   // forward norm 1/100 folded in
    ct[2 * m + 1] = s * 0.01;
  }
}

// =================== fused encoder + 50-step GRU decoder ===================
// 128 rows/block, 512 thr (8 waves). wave = (rg: row-half of 64) x (cg: col-quarter).
// LDS 81,408 -> 2 blocks/CU. __launch_bounds__(512,2): HW-verified (R1 vs R2/R3) that the
// 2nd arg acts CUDA-style (min BLOCKS/CU): (512,2) -> 4 waves/EU -> 128-VGPR budget, no spill;
// (512,4) gave a 64-VGPR budget and 20 GB of scratch traffic. Do not raise it.
__global__ __launch_bounds__(512, 2) void fused_kernel(
    const float* __restrict__ enc_in, const unsigned char* __restrict__ ws,
    float* __restrict__ out)
{
  __shared__ __align__(16) unsigned char smem[SMEM_BYTES];
  _Float16* Hb    = (_Float16*)smem;                   // [128][212]
  _Float16* Y1    = (_Float16*)(smem + Y1_OFF);        // [128][104]
  float*    DECIN = (float*)(smem + DECIN_OFF);        // [128]

  const _Float16* Wbig = (const _Float16*)(ws + WBIG_OFF);
  const _Float16* W2w  = (const _Float16*)(ws + W2_OFF);
  const _Float16* We1  = (const _Float16*)(ws + WE1_OFF);
  const _Float16* We2  = (const _Float16*)(ws + WE2_OFF);
  const _Float16* Wel  = (const _Float16*)(ws + WEL_OFF);
  const float* wihc = (const float*)(ws + WIHC_OFF);
  const float* bsum = (const float*)(ws + BSUM_OFF);
  const float* bhhn = (const float*)(ws + BHHN_OFF);
  const float* b1p  = (const float*)(ws + B1P_OFF);
  const float* b2p  = (const float*)(ws + B2P_OFF);
  const float* w3p  = (const float*)(ws + W3P_OFF);
  const float* be1  = (const float*)(ws + BE1_OFF);
  const float* be2  = (const float*)(ws + BE2_OFF);
  const float* bel  = (const float*)(ws + BEL_OFF);
  const float b3v   = *(const float*)(ws + B3_OFF);

  const int tid = threadIdx.x;
  const int lane = tid & 63, wv = tid >> 6;
  const int q = lane >> 4, c = lane & 15;
  const int rg = wv >> 2, cg = wv & 3;
  const int row0 = blockIdx.x * 128;
  const half8 Z8 = {};

  // ---------------- ENCODER: 2 sub-rounds of 64 rows ----------------
#pragma unroll 1
  for (int sub = 0; sub < 2; ++sub) {
    float*    XF   = (float*)(smem + sub * 27136);        // [64][101] inside Hb half
    _Float16* X1   = (_Float16*)(smem + sub * 27136);     // [64][104] (after DFT)
    _Float16* SIGX = (_Float16*)(smem + Y1_OFF);          // [64][208] (Y1 region); X2 overlays
    __syncthreads();
    for (int i = tid; i < 6400; i += 512) {
      int r = i / 100, t = i - r * 100;
      XF[r * 101 + t] = enc_in[(size_t)(row0 + sub * 64 + r) * 100 + t];
    }
    {
      const double* ctg = (const double*)(ws + CT_OFF);
      for (int i = tid; i < 100; i += 512) {
        double* d = (double*)(smem + Y1_OFF + ((i >> 3) * 416 + (i & 7) * 16));
        d[0] = ctg[2 * i]; d[1] = ctg[2 * i + 1];
      }
    }
    __syncthreads();
    // --- fp64 DFT (sign-safe angles); lane = row, wave-uniform bin ---
    for (int kb = wv; kb < 51; kb += 8) {
      double re = 0.0, im = 0.0; int m = 0;
      const float* xr = XF + lane * 101;
      for (int t = 0; t < 100; ++t) {
        const double* cp = (const double*)(smem + Y1_OFF + ((m >> 3) * 416 + (m & 7) * 16));
        double x = (double)xr[t];
        re = fma(x, cp[0], re);
        im = fma(x, cp[1], im);
        m += kb; if (m >= 100) m -= 100;
      }
      if (kb == 0 || kb == 50) im = 0.0;             // match pocketfft exact-real DC/Nyquist
      float ab = (float)sqrt(re * re + im * im);
      float an = atan2f((float)im, (float)re);
      SIGX[lane * 208 + 100 + kb] = (_Float16)ab;
      SIGX[lane * 208 + 151 + kb] = (_Float16)an;
    }
    __syncthreads();
    // time-domain cols + K-pad zeros (CT dead now)
    for (int i = tid; i < 6400; i += 512) {
      int r = i / 100, t = i - r * 100;
      SIGX[r * 208 + t] = (_Float16)XF[r * 101 + t];
    }
    for (int i = tid; i < 64 * 6; i += 512) {
      int r = i / 6; SIGX[r * 208 + 202 + (i - r * 6)] = (_Float16)0.f;
    }
    __syncthreads();
    // --- enc1: sig(K208) -> x1 ---
#pragma unroll 1
    for (int jt = wv; jt < 7; jt += 8) {
      floatx4 C[4] = {{0,0,0,0},{0,0,0,0},{0,0,0,0},{0,0,0,0}};
      const _Float16* wp = We1 + (jt * 16 + c) * 224 + q * 8;
#pragma unroll
      for (int s = 0; s < 7; ++s) {
        half8 B = g_frag(wp + s * 32);
#pragma unroll
        for (int m = 0; m < 4; ++m) {
          half8 Af = (s == 6 && q >= 2) ? Z8 : lds_frag16(SIGX + (m * 16 + c) * 208 + q * 8 + s * 32);
          C[m] = MFMA16(Af, B, C[m]);
        }
      }
      int col = jt * 16 + c; float bv = be1[col]; bool wm = col < 104;
#pragma unroll
      for (int m = 0; m < 4; ++m)
#pragma unroll
        for (int r = 0; r < 4; ++r) {
          float v = C[m][r] + bv; v = fmaxf(v, 0.01f * v);
          if (wm) X1[(m * 16 + 4 * q + r) * 104 + col] = (_Float16)v;
        }
    }
    __syncthreads();
    // --- enc2: x1(K104) -> x2 (overlays SIG region) ---
#pragma unroll 1
    for (int jt = wv; jt < 13; jt += 8) {
      floatx4 C[4] = {{0,0,0,0},{0,0,0,0},{0,0,0,0},{0,0,0,0}};
      const _Float16* wp = We2 + (jt * 16 + c) * 128 + q * 8;
#pragma unroll
      for (int s = 0; s < 4; ++s) {
        half8 B = g_frag(wp + s * 32);
#pragma unroll
        for (int m = 0; m < 4; ++m) {
          half8 Af = (s == 3 && q >= 1) ? Z8 : lds_frag16(X1 + (m * 16 + c) * 104 + q * 8 + s * 32);
          C[m] = MFMA16(Af, B, C[m]);
        }
      }
      int col = jt * 16 + c; float bv = be2[col];
#pragma unroll
      for (int m = 0; m < 4; ++m)
#pragma unroll
        for (int r = 0; r < 4; ++r) {
          float v = C[m][r] + bv; v = fmaxf(v, 0.01f * v);
          SIGX[(m * 16 + 4 * q + r) * 208 + col] = (_Float16)v;   // X2
        }
    }
    __syncthreads();
    // --- encl: x2(K208) -> h0 rows ---
#pragma unroll 1
    for (int jt = wv; jt < 13; jt += 8) {
      floatx4 C[4] = {{0,0,0,0},{0,0,0,0},{0,0,0,0},{0,0,0,0}};
      const _Float16* wp = Wel + (jt * 16 + c) * 224 + q * 8;
#pragma unroll
      for (int s = 0; s < 7; ++s) {
        half8 B = g_frag(wp + s * 32);
#pragma unroll
        for (int m = 0; m < 4; ++m) {
          half8 Af = (s == 6 && q >= 2) ? Z8 : lds_frag16(SIGX + (m * 16 + c) * 208 + q * 8 + s * 32);
          C[m] = MFMA16(Af, B, C[m]);
        }
      }
      int col = jt * 16 + c; float bv = bel[col]; bool wm = col < 200;
#pragma unroll
      for (int m = 0; m < 4; ++m)
#pragma unroll
        for (int r = 0; r < 4; ++r) {
          float v = C[m][r] + bv;
          if (wm) Hb[(sub * 64 + m * 16 + 4 * q + r) * 212 + col] = (_Float16)v;
        }
    }
  }
  __syncthreads();
  // zero Hb K-pad cols 200..211 (scratch overwrote them) + dec_in0
  for (int i = tid; i < 128 * 12; i += 512) {
    int r = i / 12; Hb[r * 212 + 200 + (i - r * 12)] = (_Float16)0.f;
  }
  for (int i = tid; i < 128; i += 512)
    DECIN[i] = enc_in[(size_t)(row0 + i) * 100 + 99];
  __syncthreads();

  // ---------------- DECODER: 51 iterations, 4 barriers each ----------------
#pragma unroll 1
  for (int k = 0; k <= 50; ++k) {
    if (k >= 1) {
      // ---- phase A: y1 = lrelu(h_k @ dec_w1^T + b1); wave (rg,cg): rows rg*64.., jt = cg, cg+4 ----
#pragma unroll
      for (int ji = 0; ji < 2; ++ji) {
        int jt = cg + ji * 4;
        if (jt < 7) {
          floatx4 C[4] = {{0,0,0,0},{0,0,0,0},{0,0,0,0},{0,0,0,0}};
          const _Float16* wp = Wbig + (624 + jt * 16 + c) * 224 + q * 8;
#pragma unroll
          for (int s = 0; s < 7; ++s) {
            half8 B = g_frag(wp + s * 32);
#pragma unroll
            for (int m = 0; m < 4; ++m) {
              half8 Af = (s == 6 && q >= 2) ? Z8 : lds_frag(Hb + (rg * 64 + m * 16 + c) * 212 + q * 8 + s * 32);
              C[m] = MFMA16(Af, B, C[m]);
            }
          }
          int col = jt * 16 + c; float bv = b1p[col]; bool wm = col < 104;
#pragma unroll
          for (int m = 0; m < 4; ++m)
#pragma unroll
            for (int r = 0; r < 4; ++r) {
              float v = C[m][r] + bv; v = fmaxf(v, 0.01f * v);
              if (wm) Y1[(rg * 64 + m * 16 + 4 * q + r) * 104 + col] = (_Float16)v;
            }
        }
      }
      __syncthreads();
      // ---- phase B (waves 0,1 only): y2 -> y3 -> y_{k-1}; wave wv: rows wv*64..+63 ----
      if (wv < 2) {
        float ya[4][4] = {{0,0,0,0},{0,0,0,0},{0,0,0,0},{0,0,0,0}};
#pragma unroll 1
        for (int jt = 0; jt < 4; ++jt) {
          half8 Bw[4];
          const _Float16* wp = W2w + (jt * 16 + c) * 128 + q * 8;
#pragma unroll
          for (int s = 0; s < 4; ++s) Bw[s] = g_frag(wp + s * 32);
          int col = jt * 16 + c; float b2v = b2p[col], w3v = w3p[col];
#pragma unroll
          for (int m = 0; m < 4; ++m) {
            floatx4 Cy = {0.f, 0.f, 0.f, 0.f};
#pragma unroll
            for (int s = 0; s < 4; ++s) {
              half8 A2 = (s == 3 && q >= 1) ? Z8 : lds_frag16(Y1 + (wv * 64 + m * 16 + c) * 104 + q * 8 + s * 32);
              Cy = MFMA16(A2, Bw[s], Cy);
            }
#pragma unroll
            for (int r = 0; r < 4; ++r) {
              float v = Cy[r] + b2v; v = fmaxf(v, 0.01f * v);
              ya[m][r] = fmaf(v, w3v, ya[m][r]);
            }
          }
        }
#pragma unroll
        for (int m = 0; m < 4; ++m)
#pragma unroll
          for (int r = 0; r < 4; ++r) {
            float v = ya[m][r];
            v += __shfl_xor(v, 1); v += __shfl_xor(v, 2);
            v += __shfl_xor(v, 4); v += __shfl_xor(v, 8);
            if (c == 0) {
              int rowL = wv * 64 + m * 16 + 4 * q + r;
              float y = v + b3v;
              DECIN[rowL] = y;
              out[(size_t)(row0 + rowL) * 50 + (k - 1)] = y;
            }
          }
      }
      __syncthreads();
    }
    if (k <= 49) {
      // ---- phase C: 3-gate GEMM + GRU update; h_new carried in statically-indexed regs ----
      unsigned hn4[4][4][2];   // [ji][m][pair] — all indices static (full unroll)
#pragma unroll
      for (int ji = 0; ji < 4; ++ji) {
        int jt = cg + ji * 4;
        if (jt < 13) {
          const _Float16* wp = Wbig + (jt * 16 + c) * 224 + q * 8;
          floatx4 Cr[4] = {{0,0,0,0},{0,0,0,0},{0,0,0,0},{0,0,0,0}};
          floatx4 Cz[4] = {{0,0,0,0},{0,0,0,0},{0,0,0,0},{0,0,0,0}};
          floatx4 Cn[4] = {{0,0,0,0},{0,0,0,0},{0,0,0,0},{0,0,0,0}};
#pragma unroll
          for (int s = 0; s < 7; ++s) {
            half8 Br = g_frag(wp + s * 32);
            half8 Bz = g_frag(wp + 208 * 224 + s * 32);
            half8 Bn = g_frag(wp + 416 * 224 + s * 32);
#pragma unroll
            for (int m = 0; m < 4; ++m) {
              half8 Af = (s == 6 && q >= 2) ? Z8 : lds_frag(Hb + (rg * 64 + m * 16 + c) * 212 + q * 8 + s * 32);
              Cr[m] = MFMA16(Af, Br, Cr[m]);
              Cz[m] = MFMA16(Af, Bz, Cz[m]);
              Cn[m] = MFMA16(Af, Bn, Cn[m]);
            }
          }
          int col = jt * 16 + c;
          float wr = wihc[col], wz = wihc[208 + col], wn = wihc[416 + col];
          float br = bsum[col], bz = bsum[208 + col], bnih = bsum[416 + col];
          float bnhh = bhhn[col];
#pragma unroll
          for (int m = 0; m < 4; ++m) {
            int rbase = (rg * 64 + m * 16 + 4 * q) * 212 + col;
            float hv[4];
#pragma unroll
            for (int r = 0; r < 4; ++r) {
              float d = DECIN[rg * 64 + m * 16 + 4 * q + r];
              float rgate = sigm(Cr[m][r] + fmaf(d, wr, br));
              float zgate = sigm(Cz[m][r] + fmaf(d, wz, bz));
              float ngate = tanh_(fmaf(d, wn, bnih) + rgate * (Cn[m][r] + bnhh));
              float ho = (float)Hb[rbase + r * 212];
              hv[r] = fmaf(zgate, ho - ngate, ngate);
            }
            hn4[ji][m][0] = pack2(hv[0], hv[1]);
            hn4[ji][m][1] = pack2(hv[2], hv[3]);
          }
        }
      }
      __syncthreads();   // all reads of h_k complete before any h_{k+1} write
#pragma unroll
      for (int ji = 0; ji < 4; ++ji) {
        int jt = cg + ji * 4;
        int col = jt * 16 + c;
        bool wm = (jt < 13) && (col < 200);
#pragma unroll
        for (int m = 0; m < 4; ++m)
#pragma unroll
          for (int rr = 0; rr < 2; ++rr) {
            unsigned u = hn4[ji][m][rr];
            int row = rg * 64 + m * 16 + 4 * q + rr * 2;
            if (wm) {
              Hb[row * 212 + col]       = unpk(u, 0);
              Hb[(row + 1) * 212 + col] = unpk(u, 1);
            }
          }
      }
    }
    __syncthreads();
  }
}

extern "C" void kernel_launch(void* const* d_in, const int* in_sizes, int n_in,
                              void* d_out, int out_size, void* d_ws, size_t ws_size,
                              hipStream_t stream) {
  const float* enc_in = (const float*)d_in[0];
  const float* enc_w1 = (const float*)d_in[1];
  const float* enc_b1 = (const float*)d_in[2];
  const float* enc_w2 = (const float*)d_in[3];
  const float* enc_b2 = (const float*)d_in[4];
  const float* enc_wl = (const float*)d_in[5];
  const float* enc_bl = (const float*)d_in[6];
  const float* w_ih   = (const float*)d_in[7];
  const float* w_hh   = (const float*)d_in[8];
  const float* b_ih   = (const float*)d_in[9];
  const float* b_hh   = (const float*)d_in[10];
  const float* dw1    = (const float*)d_in[11];
  const float* db1    = (const float*)d_in[12];
  const float* dw2    = (const float*)d_in[13];
  const float* db2    = (const float*)d_in[14];
  const float* dw3    = (const float*)d_in[15];
  const float* db3    = (const float*)d_in[16];
  unsigned char* ws = (unsigned char*)d_ws;
  float* out = (float*)d_out;

  prep_kernel<<<dim3(256), dim3(256), 0, stream>>>(
      enc_w1, enc_b1, enc_w2, enc_b2, enc_wl, enc_bl,
      w_ih, w_hh, b_ih, b_hh, dw1, db1, dw2, db2, dw3, db3, ws);
  fused_kernel<<<dim3(1024), dim3(512), 0, stream>>>(enc_in, ws, out);
}

// Round 5
// 5390.426 us; speedup vs baseline: 3.4582x; 2.8217x over previous
//
#include <hip/hip_runtime.h>
#include <math.h>

typedef _Float16 half8  __attribute__((ext_vector_type(8)));
typedef float    floatx4 __attribute__((ext_vector_type(4)));

#define MFMA16(a, b, c) __builtin_amdgcn_mfma_f32_16x16x32_f16((a), (b), (c), 0, 0, 0)

// ---------------- workspace layout (bytes) ----------------
constexpr unsigned WBIG_OFF = 0;          // f16 [736][224]  rows: 0..207 Wr, 208..415 Wz, 416..623 Wn, 624..735 dec_w1
constexpr unsigned W2_OFF   = 329728;     // f16 [64][128]   dec_w2^ (row=y2col, col=k)
constexpr unsigned WE1_OFF  = 346112;     // f16 [112][224]  enc_w1
constexpr unsigned WE2_OFF  = 396288;     // f16 [208][128]  enc_w2
constexpr unsigned WEL_OFF  = 449536;     // f16 [208][224]  enc_wl
constexpr unsigned WIHC_OFF = 542720;     // f32 [624]  w_ih column (gate-padded)
constexpr unsigned BSUM_OFF = 545216;     // f32 [624]  r,z: b_ih+b_hh ; n: b_ih
constexpr unsigned BHHN_OFF = 547712;     // f32 [208]  b_hh (n gate)
constexpr unsigned B1P_OFF  = 548544;     // f32 [112]
constexpr unsigned B2P_OFF  = 548992;     // f32 [64]
constexpr unsigned W3P_OFF  = 549248;     // f32 [64]
constexpr unsigned BE1_OFF  = 549504;     // f32 [112]
constexpr unsigned BE2_OFF  = 549952;     // f32 [208]
constexpr unsigned BEL_OFF  = 550784;     // f32 [208]
constexpr unsigned B3_OFF   = 551616;     // f32 [1] (+pad)
constexpr unsigned CT_OFF   = 551632;     // f64 [100][2] twiddles (cos,sin)/100, exact zeros forced
constexpr unsigned WS_NEED  = 553232;

// ---------------- LDS layout (bytes) ----------------
// Hb f16 [256][212] @0 (108544) — row slice [wv*64 .. wv*64+63] PRIVATE to wave wv in decoder
// SIG f16 [64][208] @108544 (26624) — encoder scratch only
// CHK f16 4 x [64][32] @135168 (16384) — per-wave C->A transpose chunk
// DECIN f32 [256] @151552 (1024)
// CT f64 [200] @152576 (1600)
constexpr unsigned SIG_OFF   = 108544;
constexpr unsigned CHK_OFF   = 135168;
constexpr unsigned DECIN_OFF = 151552;
constexpr unsigned CTL_OFF   = 152576;
constexpr unsigned SMEM_BYTES = 154176;   // 1 block/CU

__device__ __forceinline__ half8 lds_frag(const _Float16* p) {
  // Hb stride 212 f16 = 424B -> 8B-aligned, two ds_read_b64
  union { uint2 u[2]; half8 h; } cv;
  cv.u[0] = *(const uint2*)p;
  cv.u[1] = *(const uint2*)(p + 4);
  return cv.h;
}
__device__ __forceinline__ half8 lds_frag16(const _Float16* p) {
  // 16B-aligned rows (stride 32/104/208 f16) -> ds_read_b128
  union { uint4 u; half8 h; } cv;
  cv.u = *(const uint4*)p;
  return cv.h;
}
__device__ __forceinline__ half8 g_frag(const _Float16* p) {
  union { uint4 u; half8 h; } cv;
  cv.u = *(const uint4*)p;      // global_load_dwordx4
  return cv.h;
}
__device__ __forceinline__ float sigm(float x) {
  return __builtin_amdgcn_rcpf(1.f + __builtin_amdgcn_exp2f(-1.44269504f * x));
}
__device__ __forceinline__ float tanh_(float x) {
  return 1.f - 2.f * __builtin_amdgcn_rcpf(1.f + __builtin_amdgcn_exp2f(2.88539008f * x));
}

// =================== prep: pack weights to fp16, build twiddles ===================
__global__ __launch_bounds__(256) void prep_kernel(
    const float* __restrict__ enc_w1, const float* __restrict__ enc_b1,
    const float* __restrict__ enc_w2, const float* __restrict__ enc_b2,
    const float* __restrict__ enc_wl, const float* __restrict__ enc_bl,
    const float* __restrict__ w_ih,  const float* __restrict__ w_hh,
    const float* __restrict__ b_ih,  const float* __restrict__ b_hh,
    const float* __restrict__ dw1, const float* __restrict__ db1,
    const float* __restrict__ dw2, const float* __restrict__ db2,
    const float* __restrict__ dw3, const float* __restrict__ db3,
    unsigned char* __restrict__ ws)
{
  const int g = blockIdx.x * blockDim.x + threadIdx.x;
  const int st = gridDim.x * blockDim.x;
  _Float16* Wbig = (_Float16*)(ws + WBIG_OFF);
  for (int i = g; i < 736 * 224; i += st) {
    int row = i / 224, k = i - row * 224;
    float v = 0.f;
    if (k < 200) {
      if (row < 624) { int gg = row / 208, j = row - gg * 208;
        if (j < 200) v = w_hh[(gg * 200 + j) * 200 + k]; }
      else { int j = row - 624; if (j < 100) v = dw1[j * 200 + k]; }
    }
    Wbig[i] = (_Float16)v;
  }
  _Float16* W2 = (_Float16*)(ws + W2_OFF);
  for (int i = g; i < 64 * 128; i += st) {
    int r = i / 128, k = i - r * 128;
    W2[i] = (_Float16)((r < 50 && k < 100) ? dw2[r * 100 + k] : 0.f);
  }
  _Float16* We1 = (_Float16*)(ws + WE1_OFF);
  for (int i = g; i < 112 * 224; i += st) {
    int r = i / 224, k = i - r * 224;
    We1[i] = (_Float16)((r < 100 && k < 202) ? enc_w1[r * 202 + k] : 0.f);
  }
  _Float16* We2 = (_Float16*)(ws + WE2_OFF);
  for (int i = g; i < 208 * 128; i += st) {
    int r = i / 128, k = i - r * 128;
    We2[i] = (_Float16)((r < 202 && k < 100) ? enc_w2[r * 100 + k] : 0.f);
  }
  _Float16* Wel = (_Float16*)(ws + WEL_OFF);
  for (int i = g; i < 208 * 224; i += st) {
    int r = i / 224, k = i - r * 224;
    Wel[i] = (_Float16)((r < 200 && k < 202) ? enc_wl[r * 202 + k] : 0.f);
  }
  float* wihc = (float*)(ws + WIHC_OFF);
  float* bsum = (float*)(ws + BSUM_OFF);
  for (int i = g; i < 624; i += st) {
    int gg = i / 208, j = i - gg * 208;
    wihc[i] = (j < 200) ? w_ih[gg * 200 + j] : 0.f;
    float b = 0.f;
    if (j < 200) b = (gg < 2) ? (b_ih[gg * 200 + j] + b_hh[gg * 200 + j]) : b_ih[400 + j];
    bsum[i] = b;
  }
  float* bhhn = (float*)(ws + BHHN_OFF);
  for (int i = g; i < 208; i += st) bhhn[i] = (i < 200) ? b_hh[400 + i] : 0.f;
  float* b1p = (float*)(ws + B1P_OFF);
  for (int i = g; i < 112; i += st) b1p[i] = (i < 100) ? db1[i] : 0.f;
  float* b2p = (float*)(ws + B2P_OFF);
  for (int i = g; i < 64; i += st) b2p[i] = (i < 50) ? db2[i] : 0.f;
  float* w3p = (float*)(ws + W3P_OFF);
  for (int i = g; i < 64; i += st) w3p[i] = (i < 50) ? dw3[i] : 0.f;
  float* be1 = (float*)(ws + BE1_OFF);
  for (int i = g; i < 112; i += st) be1[i] = (i < 100) ? enc_b1[i] : 0.f;
  float* be2 = (float*)(ws + BE2_OFF);
  for (int i = g; i < 208; i += st) be2[i] = (i < 202) ? enc_b2[i] : 0.f;
  float* bel = (float*)(ws + BEL_OFF);
  for (int i = g; i < 208; i += st) bel[i] = (i < 200) ? enc_bl[i] : 0.f;
  if (g == 0) *(float*)(ws + B3_OFF) = db3[0];
  double* ct = (double*)(ws + CT_OFF);
  for (int m = g; m < 100; m += st) {
    double c, s;
    if      (m == 0)  { c = 1.0;  s = 0.0; }
    else if (m == 25) { c = 0.0;  s = -1.0; }
    else if (m == 50) { c = -1.0; s = 0.0; }
    else if (m == 75) { c = 0.0;  s = 1.0; }
    else { double a = -2.0 * 3.14159265358979323846 * (double)m / 100.0; c = cos(a); s = sin(a); }
    ct[2 * m]     = c * 0.01;   // forward norm 1/100 folded in
    ct[2 * m + 1] = s * 0.01;
  }
}

// =================== fused encoder + barrier-free row-split GRU decoder ===================
// 256 thr (4 waves), 256 rows/block. Decoder: wave wv PRIVATELY owns rows wv*64..wv*64+63
// (h in 112 persistent A-frag VGPRs + its Hb LDS slice) -> ZERO __syncthreads in the 51-iter
// loop; all ordering is per-wave s_waitcnt. 1 block/CU (LDS 154KB), 1 wave/SIMD,
// launch_bounds(256,1) -> ~512-reg unified budget, no spill.
__global__ __launch_bounds__(256, 1) void fused_kernel(
    const float* __restrict__ enc_in, const unsigned char* __restrict__ ws,
    float* __restrict__ out)
{
  __shared__ __align__(16) unsigned char smem[SMEM_BYTES];
  _Float16* Hb    = (_Float16*)smem;                   // [256][212]
  _Float16* SIG   = (_Float16*)(smem + SIG_OFF);       // [64][208] enc scratch
  float*    DECIN = (float*)(smem + DECIN_OFF);        // [256]
  double*   CTL   = (double*)(smem + CTL_OFF);         // [200]

  const _Float16* Wbig = (const _Float16*)(ws + WBIG_OFF);
  const _Float16* W2w  = (const _Float16*)(ws + W2_OFF);
  const _Float16* We1  = (const _Float16*)(ws + WE1_OFF);
  const _Float16* We2  = (const _Float16*)(ws + WE2_OFF);
  const _Float16* Wel  = (const _Float16*)(ws + WEL_OFF);
  const float* wihc = (const float*)(ws + WIHC_OFF);
  const float* bsum = (const float*)(ws + BSUM_OFF);
  const float* bhhn = (const float*)(ws + BHHN_OFF);
  const float* b1p  = (const float*)(ws + B1P_OFF);
  const float* b2p  = (const float*)(ws + B2P_OFF);
  const float* w3p  = (const float*)(ws + W3P_OFF);
  const float* be1  = (const float*)(ws + BE1_OFF);
  const float* be2  = (const float*)(ws + BE2_OFF);
  const float* bel  = (const float*)(ws + BEL_OFF);
  const float b3v   = *(const float*)(ws + B3_OFF);

  const int tid = threadIdx.x;
  const int lane = tid & 63, wv = tid >> 6;     // 4 waves
  const int q = lane >> 4, c = lane & 15;
  const int row0 = blockIdx.x * 256;
  const half8 Z8 = {};

  // twiddles -> LDS (persist through encoder)
  {
    const double* ctg = (const double*)(ws + CT_OFF);
    for (int i = tid; i < 200; i += 256) CTL[i] = ctg[i];
  }

  // ---------------- ENCODER: 4 sub-rounds of 64 rows (cooperative, barriers OK) ----------------
#pragma unroll 1
  for (int sub = 0; sub < 4; ++sub) {
    float*    XF = (float*)(smem + sub * 27136);        // [64][101] in wave-sub's Hb slice
    _Float16* X1 = (_Float16*)(smem + sub * 27136);     // [64][104] overlays XF after DFT
    __syncthreads();
    for (int i = tid; i < 6400; i += 256) {
      int r = i / 100, t = i - r * 100;
      XF[r * 101 + t] = enc_in[(size_t)(row0 + sub * 64 + r) * 100 + t];
    }
    for (int i = tid; i < 64 * 6; i += 256) {           // zero SIG pad cols 202..207
      int r = i / 6; SIG[r * 208 + 202 + (i - r * 6)] = (_Float16)0.f;
    }
    __syncthreads();
    // fp64 DFT (sign-safe angles); lane = row, wave-uniform bin; + time-domain copy
    for (int kb = wv; kb < 51; kb += 4) {
      double re = 0.0, im = 0.0; int m = 0;
      const float* xr = XF + lane * 101;
      for (int t = 0; t < 100; ++t) {
        double x = (double)xr[t];
        re = fma(x, CTL[2 * m], re);
        im = fma(x, CTL[2 * m + 1], im);
        m += kb; if (m >= 100) m -= 100;
      }
      if (kb == 0 || kb == 50) im = 0.0;             // match pocketfft exact-real DC/Nyquist
      float ab = (float)sqrt(re * re + im * im);
      float an = atan2f((float)im, (float)re);
      SIG[lane * 208 + 100 + kb] = (_Float16)ab;
      SIG[lane * 208 + 151 + kb] = (_Float16)an;
    }
    for (int i = tid; i < 6400; i += 256) {
      int r = i / 100, t = i - r * 100;
      SIG[r * 208 + t] = (_Float16)XF[r * 101 + t];
    }
    __syncthreads();
    // enc1: sig(K208) -> x1 (overlays XF)
#pragma unroll 1
    for (int jt = wv; jt < 7; jt += 4) {
      floatx4 C[4] = {{0,0,0,0},{0,0,0,0},{0,0,0,0},{0,0,0,0}};
      const _Float16* wp = We1 + (jt * 16 + c) * 224 + q * 8;
#pragma unroll
      for (int s = 0; s < 7; ++s) {
        half8 B = g_frag(wp + s * 32);
#pragma unroll
        for (int m = 0; m < 4; ++m) {
          half8 Af = (s == 6 && q >= 2) ? Z8 : lds_frag16(SIG + (m * 16 + c) * 208 + q * 8 + s * 32);
          C[m] = MFMA16(Af, B, C[m]);
        }
      }
      int col = jt * 16 + c; float bv = be1[col]; bool wm = col < 104;
#pragma unroll
      for (int m = 0; m < 4; ++m)
#pragma unroll
        for (int r = 0; r < 4; ++r) {
          float v = C[m][r] + bv; v = fmaxf(v, 0.01f * v);
          if (wm) X1[(m * 16 + 4 * q + r) * 104 + col] = (_Float16)v;
        }
    }
    __syncthreads();
    // enc2: x1(K104) -> x2 (overlays SIG)
#pragma unroll 1
    for (int jt = wv; jt < 13; jt += 4) {
      floatx4 C[4] = {{0,0,0,0},{0,0,0,0},{0,0,0,0},{0,0,0,0}};
      const _Float16* wp = We2 + (jt * 16 + c) * 128 + q * 8;
#pragma unroll
      for (int s = 0; s < 4; ++s) {
        half8 B = g_frag(wp + s * 32);
#pragma unroll
        for (int m = 0; m < 4; ++m) {
          half8 Af = (s == 3 && q >= 1) ? Z8 : lds_frag16(X1 + (m * 16 + c) * 104 + q * 8 + s * 32);
          C[m] = MFMA16(Af, B, C[m]);
        }
      }
      int col = jt * 16 + c; float bv = be2[col];
#pragma unroll
      for (int m = 0; m < 4; ++m)
#pragma unroll
        for (int r = 0; r < 4; ++r) {
          float v = C[m][r] + bv; v = fmaxf(v, 0.01f * v);
          SIG[(m * 16 + 4 * q + r) * 208 + col] = (_Float16)v;   // X2
        }
    }
    __syncthreads();
    // encl: x2(K208) -> h0 (overwrites X1/XF scratch in wave-sub's slice)
#pragma unroll 1
    for (int jt = wv; jt < 13; jt += 4) {
      floatx4 C[4] = {{0,0,0,0},{0,0,0,0},{0,0,0,0},{0,0,0,0}};
      const _Float16* wp = Wel + (jt * 16 + c) * 224 + q * 8;
#pragma unroll
      for (int s = 0; s < 7; ++s) {
        half8 B = g_frag(wp + s * 32);
#pragma unroll
        for (int m = 0; m < 4; ++m) {
          half8 Af = (s == 6 && q >= 2) ? Z8 : lds_frag16(SIG + (m * 16 + c) * 208 + q * 8 + s * 32);
          C[m] = MFMA16(Af, B, C[m]);
        }
      }
      int col = jt * 16 + c; float bv = bel[col]; bool wm = col < 200;
#pragma unroll
      for (int m = 0; m < 4; ++m)
#pragma unroll
        for (int r = 0; r < 4; ++r) {
          float v = C[m][r] + bv;
          if (wm) Hb[(sub * 64 + m * 16 + 4 * q + r) * 212 + col] = (_Float16)v;
        }
    }
  }
  __syncthreads();
  // zero Hb K-pad cols 200..211 + dec_in0
  for (int i = tid; i < 256 * 12; i += 256) {
    int r = i / 12; Hb[r * 212 + 200 + (i - r * 12)] = (_Float16)0.f;
  }
  for (int i = tid; i < 256; i += 256)
    DECIN[i] = enc_in[(size_t)(row0 + i) * 100 + 99];
  __syncthreads();   // last barrier — decoder below is barrier-free

  // ---------------- DECODER: 51 iterations, wave-private, NO barriers ----------------
  _Float16* myH   = Hb + wv * 64 * 212;                         // own 64 rows
  _Float16* myCHK = (_Float16*)(smem + CHK_OFF) + wv * 2048;    // own [64][32] chunk
  const int rbO = wv * 64;

#pragma unroll 1
  for (int k = 0; k <= 50; ++k) {
    // refresh persistent A-frags of h_k from own LDS slice
    half8 A[4][7];
#pragma unroll
    for (int m = 0; m < 4; ++m)
#pragma unroll
      for (int s = 0; s < 7; ++s)
        A[m][s] = (s == 6 && q >= 2) ? Z8 : lds_frag(myH + (m * 16 + c) * 212 + q * 8 + s * 32);

    if (k >= 1) {
      // ---- y1 = lrelu(h_k @ dec_w1^T + b1), C->A transform per 32-col chunk (wave-private) ----
      half8 A2[4][4];
#pragma unroll
      for (int s2 = 0; s2 < 4; ++s2) {
#pragma unroll
        for (int jj = 0; jj < 2; ++jj) {
          int jt = 2 * s2 + jj;
          if (jt < 7) {
            floatx4 C[4] = {{0,0,0,0},{0,0,0,0},{0,0,0,0},{0,0,0,0}};
            const _Float16* wp = Wbig + (624 + jt * 16 + c) * 224 + q * 8;
#pragma unroll
            for (int s = 0; s < 7; ++s) {
              half8 B = g_frag(wp + s * 32);
#pragma unroll
              for (int m = 0; m < 4; ++m) C[m] = MFMA16(A[m][s], B, C[m]);
            }
            int col = jt * 16 + c; float bv = b1p[col];
#pragma unroll
            for (int m = 0; m < 4; ++m)
#pragma unroll
              for (int r = 0; r < 4; ++r) {
                float v = C[m][r] + bv; v = fmaxf(v, 0.01f * v);
                myCHK[(m * 16 + 4 * q + r) * 32 + jj * 16 + c] = (_Float16)v;
              }
          }
        }
#pragma unroll
        for (int m = 0; m < 4; ++m)
          A2[m][s2] = (s2 == 3 && q >= 2) ? Z8 : lds_frag16(myCHK + (m * 16 + c) * 32 + q * 8);
      }
      // ---- y2 -> y3 ----
      float ya[4][4] = {{0,0,0,0},{0,0,0,0},{0,0,0,0},{0,0,0,0}};
#pragma unroll
      for (int jt2 = 0; jt2 < 4; ++jt2) {
        floatx4 Cy[4] = {{0,0,0,0},{0,0,0,0},{0,0,0,0},{0,0,0,0}};
        const _Float16* wp = W2w + (jt2 * 16 + c) * 128 + q * 8;
#pragma unroll
        for (int s2 = 0; s2 < 4; ++s2) {
          half8 B = g_frag(wp + s2 * 32);
#pragma unroll
          for (int m = 0; m < 4; ++m) Cy[m] = MFMA16(A2[m][s2], B, Cy[m]);
        }
        int col2 = jt2 * 16 + c; float b2v = b2p[col2], w3v = w3p[col2];
#pragma unroll
        for (int m = 0; m < 4; ++m)
#pragma unroll
          for (int r = 0; r < 4; ++r) {
            float v = Cy[m][r] + b2v; v = fmaxf(v, 0.01f * v);
            ya[m][r] = fmaf(v, w3v, ya[m][r]);
          }
      }
#pragma unroll
      for (int m = 0; m < 4; ++m)
#pragma unroll
        for (int r = 0; r < 4; ++r) {
          float v = ya[m][r];
          v += __shfl_xor(v, 1); v += __shfl_xor(v, 2);
          v += __shfl_xor(v, 4); v += __shfl_xor(v, 8);
          if (c == 0) {
            int rowL = m * 16 + 4 * q + r;
            float y = v + b3v;
            DECIN[rbO + rowL] = y;
            out[(size_t)(row0 + rbO + rowL) * 50 + (k - 1)] = y;
          }
        }
    }
    if (k <= 49) {
      // ---- 3-gate GEMM + GRU update, all columns, own rows: direct in-place h write ----
      float dreg[16];
#pragma unroll
      for (int m = 0; m < 4; ++m)
#pragma unroll
        for (int r = 0; r < 4; ++r)
          dreg[m * 4 + r] = DECIN[rbO + m * 16 + 4 * q + r];
#pragma unroll 1
      for (int jt = 0; jt < 13; ++jt) {
        const _Float16* wp = Wbig + (jt * 16 + c) * 224 + q * 8;
        half8 Bfr[7], Bfz[7], Bfn[7];
#pragma unroll
        for (int s = 0; s < 7; ++s) {
          Bfr[s] = g_frag(wp + s * 32);
          Bfz[s] = g_frag(wp + 208 * 224 + s * 32);
          Bfn[s] = g_frag(wp + 416 * 224 + s * 32);
        }
        floatx4 Cr[4] = {{0,0,0,0},{0,0,0,0},{0,0,0,0},{0,0,0,0}};
        floatx4 Cz[4] = {{0,0,0,0},{0,0,0,0},{0,0,0,0},{0,0,0,0}};
        floatx4 Cn[4] = {{0,0,0,0},{0,0,0,0},{0,0,0,0},{0,0,0,0}};
#pragma unroll
        for (int s = 0; s < 7; ++s)
#pragma unroll
          for (int m = 0; m < 4; ++m) {
            Cr[m] = MFMA16(A[m][s], Bfr[s], Cr[m]);
            Cz[m] = MFMA16(A[m][s], Bfz[s], Cz[m]);
            Cn[m] = MFMA16(A[m][s], Bfn[s], Cn[m]);
          }
        int col = jt * 16 + c;
        float wr = wihc[col], wz = wihc[208 + col], wn = wihc[416 + col];
        float br = bsum[col], bz = bsum[208 + col], bnih = bsum[416 + col];
        float bnhh = bhhn[col];
        bool wm = col < 200;
#pragma unroll
        for (int m = 0; m < 4; ++m) {
          _Float16* hp = myH + (m * 16 + 4 * q) * 212 + col;
#pragma unroll
          for (int r = 0; r < 4; ++r) {
            float d  = dreg[m * 4 + r];
            float ho = (float)hp[r * 212];
            float rgate = sigm(Cr[m][r] + fmaf(d, wr, br));
            float zgate = sigm(Cz[m][r] + fmaf(d, wz, bz));
            float ngate = tanh_(fmaf(d, wn, bnih) + rgate * (Cn[m][r] + bnhh));
            float hv = fmaf(zgate, ho - ngate, ngate);
            if (wm) hp[r * 212] = (_Float16)hv;
          }
        }
      }
    }
  }
}

extern "C" void kernel_launch(void* const* d_in, const int* in_sizes, int n_in,
                              void* d_out, int out_size, void* d_ws, size_t ws_size,
                              hipStream_t stream) {
  const float* enc_in = (const float*)d_in[0];
  const float* enc_w1 = (const float*)d_in[1];
  const float* enc_b1 = (const float*)d_in[2];
  const float* enc_w2 = (const float*)d_in[3];
  const float* enc_b2 = (const float*)d_in[4];
  const float* enc_wl = (const float*)d_in[5];
  const float* enc_bl = (const float*)d_in[6];
  const float* w_ih   = (const float*)d_in[7];
  const float* w_hh   = (const float*)d_in[8];
  const float* b_ih   = (const float*)d_in[9];
  const float* b_hh   = (const float*)d_in[10];
  const float* dw1    = (const float*)d_in[11];
  const float* db1    = (const float*)d_in[12];
  const float* dw2    = (const float*)d_in[13];
  const float* db2    = (const float*)d_in[14];
  const float* dw3    = (const float*)d_in[15];
  const float* db3    = (const float*)d_in[16];
  unsigned char* ws = (unsigned char*)d_ws;
  float* out = (float*)d_out;

  prep_kernel<<<dim3(256), dim3(256), 0, stream>>>(
      enc_w1, enc_b1, enc_w2, enc_b2, enc_wl, enc_bl,
      w_ih, w_hh, b_ih, b_hh, dw1, db1, dw2, db2, dw3, db3, ws);
  fused_kernel<<<dim3(512), dim3(256), 0, stream>>>(enc_in, ws, out);
}

// Round 6
// 3619.484 us; speedup vs baseline: 5.1503x; 1.4893x over previous
//
#include <hip/hip_runtime.h>
#include <math.h>

typedef _Float16 half8  __attribute__((ext_vector_type(8)));
typedef float    floatx4 __attribute__((ext_vector_type(4)));

#define MFMA16(a, b, c) __builtin_amdgcn_mfma_f32_16x16x32_f16((a), (b), (c), 0, 0, 0)

// ---------------- workspace layout (bytes) ----------------
constexpr unsigned WBIG_OFF = 0;          // f16 [736][224]  rows: 0..207 Wr, 208..415 Wz, 416..623 Wn, 624..735 dec_w1
constexpr unsigned W2_OFF   = 329728;     // f16 [64][128]   dec_w2^ (row=y2col, col=k)
constexpr unsigned WE1_OFF  = 346112;     // f16 [112][224]  enc_w1
constexpr unsigned WE2_OFF  = 396288;     // f16 [208][128]  enc_w2
constexpr unsigned WEL_OFF  = 449536;     // f16 [208][224]  enc_wl
constexpr unsigned WIHC_OFF = 542720;     // f32 [624]  w_ih column (gate-padded)
constexpr unsigned BSUM_OFF = 545216;     // f32 [624]  r,z: b_ih+b_hh ; n: b_ih
constexpr unsigned BHHN_OFF = 547712;     // f32 [208]  b_hh (n gate)
constexpr unsigned B1P_OFF  = 548544;     // f32 [112]
constexpr unsigned B2P_OFF  = 548992;     // f32 [64]
constexpr unsigned W3P_OFF  = 549248;     // f32 [64]
constexpr unsigned BE1_OFF  = 549504;     // f32 [112]
constexpr unsigned BE2_OFF  = 549952;     // f32 [208]
constexpr unsigned BEL_OFF  = 550784;     // f32 [208]
constexpr unsigned B3_OFF   = 551616;     // f32 [1] (+pad)
constexpr unsigned CT_OFF   = 551632;     // f64 [100][2] twiddles (cos,sin)/100, exact zeros forced
constexpr unsigned WS_NEED  = 553232;

// ---------------- LDS layout (bytes) ----------------
// Hb   f16 [256][208] @0      (106496)  h state; rows wv*32..+31 private to wave wv in decoder
// BST  f16 staging     @106496 (21504)  per-jt W tile: gates [3][16][224] or dec_w1 [2][16][224]
// W2L  f16 [64][136]   @128000 (17408)  dec_w2 padded (bank spread), staged once
// CHK  f16 8x[32][32]  @145408 (16384)  per-wave C->A transpose chunks (decoder)
//      (CT f64[200] overlays @145408 during encoder)
// DECIN f32 [256]      @161792 (1024)
constexpr unsigned BST_OFF   = 106496;
constexpr unsigned W2L_OFF   = 128000;
constexpr unsigned CHK_OFF   = 145408;
constexpr unsigned DECIN_OFF = 161792;
constexpr unsigned SMEM_BYTES = 162816;   // 1 block/CU, 8 waves = 2 waves/SIMD

__device__ __forceinline__ half8 lds_frag16(const _Float16* p) {
  union { uint4 u; half8 h; } cv;
  cv.u = *(const uint4*)p;      // ds_read_b128 (all strides 16B-multiples)
  return cv.h;
}
__device__ __forceinline__ half8 g_frag(const _Float16* p) {
  union { uint4 u; half8 h; } cv;
  cv.u = *(const uint4*)p;      // global_load_dwordx4
  return cv.h;
}
__device__ __forceinline__ void gload_lds16(const _Float16* gsrc, _Float16* lds) {
  __builtin_amdgcn_global_load_lds(
      (const __attribute__((address_space(1))) unsigned int*)gsrc,
      (__attribute__((address_space(3))) unsigned int*)lds, 16, 0, 0);
}
__device__ __forceinline__ float sigm(float x) {
  return __builtin_amdgcn_rcpf(1.f + __builtin_amdgcn_exp2f(-1.44269504f * x));
}
__device__ __forceinline__ float tanh_(float x) {
  return 1.f - 2.f * __builtin_amdgcn_rcpf(1.f + __builtin_amdgcn_exp2f(2.88539008f * x));
}

// =================== prep: pack weights to fp16, build twiddles ===================
__global__ __launch_bounds__(256) void prep_kernel(
    const float* __restrict__ enc_w1, const float* __restrict__ enc_b1,
    const float* __restrict__ enc_w2, const float* __restrict__ enc_b2,
    const float* __restrict__ enc_wl, const float* __restrict__ enc_bl,
    const float* __restrict__ w_ih,  const float* __restrict__ w_hh,
    const float* __restrict__ b_ih,  const float* __restrict__ b_hh,
    const float* __restrict__ dw1, const float* __restrict__ db1,
    const float* __restrict__ dw2, const float* __restrict__ db2,
    const float* __restrict__ dw3, const float* __restrict__ db3,
    unsigned char* __restrict__ ws)
{
  const int g = blockIdx.x * blockDim.x + threadIdx.x;
  const int st = gridDim.x * blockDim.x;
  _Float16* Wbig = (_Float16*)(ws + WBIG_OFF);
  for (int i = g; i < 736 * 224; i += st) {
    int row = i / 224, k = i - row * 224;
    float v = 0.f;
    if (k < 200) {
      if (row < 624) { int gg = row / 208, j = row - gg * 208;
        if (j < 200) v = w_hh[(gg * 200 + j) * 200 + k]; }
      else { int j = row - 624; if (j < 100) v = dw1[j * 200 + k]; }
    }
    Wbig[i] = (_Float16)v;
  }
  _Float16* W2 = (_Float16*)(ws + W2_OFF);
  for (int i = g; i < 64 * 128; i += st) {
    int r = i / 128, k = i - r * 128;
    W2[i] = (_Float16)((r < 50 && k < 100) ? dw2[r * 100 + k] : 0.f);
  }
  _Float16* We1 = (_Float16*)(ws + WE1_OFF);
  for (int i = g; i < 112 * 224; i += st) {
    int r = i / 224, k = i - r * 224;
    We1[i] = (_Float16)((r < 100 && k < 202) ? enc_w1[r * 202 + k] : 0.f);
  }
  _Float16* We2 = (_Float16*)(ws + WE2_OFF);
  for (int i = g; i < 208 * 128; i += st) {
    int r = i / 128, k = i - r * 128;
    We2[i] = (_Float16)((r < 202 && k < 100) ? enc_w2[r * 100 + k] : 0.f);
  }
  _Float16* Wel = (_Float16*)(ws + WEL_OFF);
  for (int i = g; i < 208 * 224; i += st) {
    int r = i / 224, k = i - r * 224;
    Wel[i] = (_Float16)((r < 200 && k < 202) ? enc_wl[r * 202 + k] : 0.f);
  }
  float* wihc = (float*)(ws + WIHC_OFF);
  float* bsum = (float*)(ws + BSUM_OFF);
  for (int i = g; i < 624; i += st) {
    int gg = i / 208, j = i - gg * 208;
    wihc[i] = (j < 200) ? w_ih[gg * 200 + j] : 0.f;
    float b = 0.f;
    if (j < 200) b = (gg < 2) ? (b_ih[gg * 200 + j] + b_hh[gg * 200 + j]) : b_ih[400 + j];
    bsum[i] = b;
  }
  float* bhhn = (float*)(ws + BHHN_OFF);
  for (int i = g; i < 208; i += st) bhhn[i] = (i < 200) ? b_hh[400 + i] : 0.f;
  float* b1p = (float*)(ws + B1P_OFF);
  for (int i = g; i < 112; i += st) b1p[i] = (i < 100) ? db1[i] : 0.f;
  float* b2p = (float*)(ws + B2P_OFF);
  for (int i = g; i < 64; i += st) b2p[i] = (i < 50) ? db2[i] : 0.f;
  float* w3p = (float*)(ws + W3P_OFF);
  for (int i = g; i < 64; i += st) w3p[i] = (i < 50) ? dw3[i] : 0.f;
  float* be1 = (float*)(ws + BE1_OFF);
  for (int i = g; i < 112; i += st) be1[i] = (i < 100) ? enc_b1[i] : 0.f;
  float* be2 = (float*)(ws + BE2_OFF);
  for (int i = g; i < 208; i += st) be2[i] = (i < 202) ? enc_b2[i] : 0.f;
  float* bel = (float*)(ws + BEL_OFF);
  for (int i = g; i < 208; i += st) bel[i] = (i < 200) ? enc_bl[i] : 0.f;
  if (g == 0) *(float*)(ws + B3_OFF) = db3[0];
  double* ct = (double*)(ws + CT_OFF);
  for (int m = g; m < 100; m += st) {
    double c, s;
    if      (m == 0)  { c = 1.0;  s = 0.0; }
    else if (m == 25) { c = 0.0;  s = -1.0; }
    else if (m == 50) { c = -1.0; s = 0.0; }
    else if (m == 75) { c = 0.0;  s = 1.0; }
    else { double a = -2.0 * 3.14159265358979323846 * (double)m / 100.0; c = cos(a); s = sin(a); }
    ct[2 * m]     = c * 0.01;   // forward norm 1/100 folded in
    ct[2 * m + 1] = s * 0.01;
  }
}

// =================== fused encoder + LDS-staged-B GRU decoder ===================
// 512 thr (8 waves, 2 waves/SIMD), 256 rows/block, 1 block/CU. Wave wv privately owns
// rows wv*32..+31 (A-frags in regs + Hb slice). Per jt, all waves cooperatively stage the
// W tile into LDS (global_load_lds w16) -> B-frags via ds_read_b128 -> L2 traffic /8.
__global__ __launch_bounds__(512, 1) void fused_kernel(
    const float* __restrict__ enc_in, const unsigned char* __restrict__ ws,
    float* __restrict__ out)
{
  __shared__ __align__(16) unsigned char smem[SMEM_BYTES];
  _Float16* Hb    = (_Float16*)smem;                       // [256][208]
  _Float16* BST   = (_Float16*)(smem + BST_OFF);
  _Float16* W2L   = (_Float16*)(smem + W2L_OFF);           // [64][136]
  float*    DECIN = (float*)(smem + DECIN_OFF);            // [256]
  double*   CTL   = (double*)(smem + CHK_OFF);             // encoder-time overlay

  const _Float16* Wbig = (const _Float16*)(ws + WBIG_OFF);
  const _Float16* W2w  = (const _Float16*)(ws + W2_OFF);
  const _Float16* We1  = (const _Float16*)(ws + WE1_OFF);
  const _Float16* We2  = (const _Float16*)(ws + WE2_OFF);
  const _Float16* Wel  = (const _Float16*)(ws + WEL_OFF);
  const float* wihc = (const float*)(ws + WIHC_OFF);
  const float* bsum = (const float*)(ws + BSUM_OFF);
  const float* bhhn = (const float*)(ws + BHHN_OFF);
  const float* b1p  = (const float*)(ws + B1P_OFF);
  const float* b2p  = (const float*)(ws + B2P_OFF);
  const float* w3p  = (const float*)(ws + W3P_OFF);
  const float* be1  = (const float*)(ws + BE1_OFF);
  const float* be2  = (const float*)(ws + BE2_OFF);
  const float* bel  = (const float*)(ws + BEL_OFF);
  const float b3v   = *(const float*)(ws + B3_OFF);

  const int tid = threadIdx.x;
  const int lane = tid & 63, wv = tid >> 6;     // 8 waves
  const int q = lane >> 4, c = lane & 15;
  const int row0 = blockIdx.x * 256;
  const half8 Z8 = {};

  // twiddles -> LDS (CHK region is decoder-only)
  {
    const double* ctg = (const double*)(ws + CT_OFF);
    for (int i = tid; i < 200; i += 512) CTL[i] = ctg[i];
  }

  // ---------------- ENCODER: 4 sub-rounds of 64 rows (cooperative) ----------------
#pragma unroll 1
  for (int sub = 0; sub < 4; ++sub) {
    float*    XF  = (float*)(smem + sub * 26624);          // [64][101] in Hb quarter
    _Float16* X1  = (_Float16*)(smem + sub * 26624);       // [64][104] overlays after DFT
    _Float16* SIG = (_Float16*)(smem + BST_OFF);           // [64][208]; X2 overlays
    __syncthreads();
    for (int i = tid; i < 6400; i += 512) {
      int r = i / 100, t = i - r * 100;
      XF[r * 101 + t] = enc_in[(size_t)(row0 + sub * 64 + r) * 100 + t];
    }
    for (int i = tid; i < 64 * 6; i += 512) {              // zero SIG pad cols 202..207
      int r = i / 6; SIG[r * 208 + 202 + (i - r * 6)] = (_Float16)0.f;
    }
    __syncthreads();
    // fp64 DFT (sign-safe angles); lane = row, wave-uniform bin
    for (int kb = wv; kb < 51; kb += 8) {
      double re = 0.0, im = 0.0; int m = 0;
      const float* xr = XF + lane * 101;
      for (int t = 0; t < 100; ++t) {
        double x = (double)xr[t];
        re = fma(x, CTL[2 * m], re);
        im = fma(x, CTL[2 * m + 1], im);
        m += kb; if (m >= 100) m -= 100;
      }
      if (kb == 0 || kb == 50) im = 0.0;          // match pocketfft exact-real DC/Nyquist
      float ab = (float)sqrt(re * re + im * im);
      float an = atan2f((float)im, (float)re);
      SIG[lane * 208 + 100 + kb] = (_Float16)ab;
      SIG[lane * 208 + 151 + kb] = (_Float16)an;
    }
    for (int i = tid; i < 6400; i += 512) {
      int r = i / 100, t = i - r * 100;
      SIG[r * 208 + t] = (_Float16)XF[r * 101 + t];
    }
    __syncthreads();
    // enc1: sig(K208) -> x1
#pragma unroll 1
    for (int jt = wv; jt < 7; jt += 8) {
      floatx4 C[4] = {{0,0,0,0},{0,0,0,0},{0,0,0,0},{0,0,0,0}};
      const _Float16* wp = We1 + (jt * 16 + c) * 224 + q * 8;
#pragma unroll
      for (int s = 0; s < 7; ++s) {
        half8 B = g_frag(wp + s * 32);
#pragma unroll
        for (int m = 0; m < 4; ++m) {
          half8 Af = (s == 6 && q >= 2) ? Z8 : lds_frag16(SIG + (m * 16 + c) * 208 + q * 8 + s * 32);
          C[m] = MFMA16(Af, B, C[m]);
        }
      }
      int col = jt * 16 + c; float bv = be1[col]; bool wm = col < 104;
#pragma unroll
      for (int m = 0; m < 4; ++m)
#pragma unroll
        for (int r = 0; r < 4; ++r) {
          float v = C[m][r] + bv; v = fmaxf(v, 0.01f * v);
          if (wm) X1[(m * 16 + 4 * q + r) * 104 + col] = (_Float16)v;
        }
    }
    __syncthreads();
    // enc2: x1(K104) -> x2 (overlays SIG)
#pragma unroll 1
    for (int jt = wv; jt < 13; jt += 8) {
      floatx4 C[4] = {{0,0,0,0},{0,0,0,0},{0,0,0,0},{0,0,0,0}};
      const _Float16* wp = We2 + (jt * 16 + c) * 128 + q * 8;
#pragma unroll
      for (int s = 0; s < 4; ++s) {
        half8 B = g_frag(wp + s * 32);
#pragma unroll
        for (int m = 0; m < 4; ++m) {
          half8 Af = (s == 3 && q >= 1) ? Z8 : lds_frag16(X1 + (m * 16 + c) * 104 + q * 8 + s * 32);
          C[m] = MFMA16(Af, B, C[m]);
        }
      }
      int col = jt * 16 + c; float bv = be2[col];
#pragma unroll
      for (int m = 0; m < 4; ++m)
#pragma unroll
        for (int r = 0; r < 4; ++r) {
          float v = C[m][r] + bv; v = fmaxf(v, 0.01f * v);
          SIG[(m * 16 + 4 * q + r) * 208 + col] = (_Float16)v;   // X2
        }
    }
    __syncthreads();
    // encl: x2(K208) -> h0 rows
#pragma unroll 1
    for (int jt = wv; jt < 13; jt += 8) {
      floatx4 C[4] = {{0,0,0,0},{0,0,0,0},{0,0,0,0},{0,0,0,0}};
      const _Float16* wp = Wel + (jt * 16 + c) * 224 + q * 8;
#pragma unroll
      for (int s = 0; s < 7; ++s) {
        half8 B = g_frag(wp + s * 32);
#pragma unroll
        for (int m = 0; m < 4; ++m) {
          half8 Af = (s == 6 && q >= 2) ? Z8 : lds_frag16(SIG + (m * 16 + c) * 208 + q * 8 + s * 32);
          C[m] = MFMA16(Af, B, C[m]);
        }
      }
      int col = jt * 16 + c; float bv = bel[col]; bool wm = col < 200;
#pragma unroll
      for (int m = 0; m < 4; ++m)
#pragma unroll
        for (int r = 0; r < 4; ++r) {
          float v = C[m][r] + bv;
          if (wm) Hb[(sub * 64 + m * 16 + 4 * q + r) * 208 + col] = (_Float16)v;
        }
    }
  }
  __syncthreads();
  // zero Hb pad cols 200..207; DECIN init; stage W2 (padded stride 136, one-time roundtrip)
  for (int i = tid; i < 256 * 8; i += 512) {
    int r = i / 8; Hb[r * 208 + 200 + (i - r * 8)] = (_Float16)0.f;
  }
  for (int i = tid; i < 256; i += 512)
    DECIN[i] = enc_in[(size_t)(row0 + i) * 100 + 99];
  for (int i = tid; i < 1024; i += 512) {
    int r = i / 16, kc = i - r * 16;
    *(uint4*)(W2L + r * 136 + kc * 8) = *(const uint4*)(W2w + r * 128 + kc * 8);
  }
  __syncthreads();   // encoder done; W2L/DECIN visible

  // ---------------- DECODER: 51 iterations; wave-private rows; cooperative B staging ----------------
  _Float16* myH   = Hb + wv * 32 * 208;
  _Float16* myCHK = (_Float16*)(smem + CHK_OFF) + wv * 1024;   // [32][32] f16

#pragma unroll 1
  for (int k = 0; k <= 50; ++k) {
    // persistent A-frags of h_k (own rows; per-wave lgkm ordering vs last iter's writes)
    half8 A[2][7];
#pragma unroll
    for (int m = 0; m < 2; ++m)
#pragma unroll
      for (int s = 0; s < 7; ++s)
        A[m][s] = (s == 6 && q >= 2) ? Z8 : lds_frag16(myH + (m * 16 + c) * 208 + s * 32 + q * 8);

    if (k >= 1) {
      // ---- y1 (dec_w1 staged per jt-pair through BST) -> CHK transpose -> A2 frags ----
      half8 A2[2][4];
#pragma unroll
      for (int jtp = 0; jtp < 4; ++jtp) {           // FULL unroll: A2[.][jtp] must stay static
        const int njt = (jtp == 3) ? 1 : 2;
        __syncthreads();                            // BST free (prev reads done)
        for (int i = wv; i < njt * 7; i += 8) {
          int jj = i / 7, p = i - jj * 7;
          gload_lds16(Wbig + (624 + (jtp * 2 + jj) * 16) * 224 + p * 512 + lane * 8,
                      BST + jj * 3584 + p * 512);
        }
        __syncthreads();                            // staged (barrier drains vmcnt)
#pragma unroll
        for (int jj = 0; jj < 2; ++jj) {
          if (jj < njt) {
            floatx4 C[2] = {{0,0,0,0},{0,0,0,0}};
#pragma unroll
            for (int s = 0; s < 7; ++s) {
              half8 B = lds_frag16(BST + jj * 3584 + c * 224 + s * 32 + q * 8);
#pragma unroll
              for (int m = 0; m < 2; ++m) C[m] = MFMA16(A[m][s], B, C[m]);
            }
            int col = (jtp * 2 + jj) * 16 + c; float bv = b1p[col];
#pragma unroll
            for (int m = 0; m < 2; ++m)
#pragma unroll
              for (int r = 0; r < 4; ++r) {
                float v = C[m][r] + bv; v = fmaxf(v, 0.01f * v);
                myCHK[(m * 16 + 4 * q + r) * 32 + jj * 16 + c] = (_Float16)v;
              }
          }
        }
#pragma unroll
        for (int m = 0; m < 2; ++m)
          A2[m][jtp] = (jtp == 3 && q >= 2) ? Z8 : lds_frag16(myCHK + (m * 16 + c) * 32 + q * 8);
      }
      // ---- y2 -> y3 (W2 resident in LDS) ----
      float ya[2][4] = {{0,0,0,0},{0,0,0,0}};
#pragma unroll
      for (int jt2 = 0; jt2 < 4; ++jt2) {
        floatx4 Cy[2] = {{0,0,0,0},{0,0,0,0}};
#pragma unroll
        for (int s2 = 0; s2 < 4; ++s2) {
          half8 B = lds_frag16(W2L + (jt2 * 16 + c) * 136 + s2 * 32 + q * 8);
#pragma unroll
          for (int m = 0; m < 2; ++m) Cy[m] = MFMA16(A2[m][s2], B, Cy[m]);
        }
        int col2 = jt2 * 16 + c; float b2v = b2p[col2], w3v = w3p[col2];
#pragma unroll
        for (int m = 0; m < 2; ++m)
#pragma unroll
          for (int r = 0; r < 4; ++r) {
            float v = Cy[m][r] + b2v; v = fmaxf(v, 0.01f * v);
            ya[m][r] = fmaf(v, w3v, ya[m][r]);
          }
      }
#pragma unroll
      for (int m = 0; m < 2; ++m)
#pragma unroll
        for (int r = 0; r < 4; ++r) {
          float v = ya[m][r];
          v += __shfl_xor(v, 1); v += __shfl_xor(v, 2);
          v += __shfl_xor(v, 4); v += __shfl_xor(v, 8);
          if (c == 0) {
            int rowL = wv * 32 + m * 16 + 4 * q + r;
            float y = v + b3v;
            DECIN[rowL] = y;
            out[(size_t)(row0 + rowL) * 50 + (k - 1)] = y;
          }
        }
    }
    if (k <= 49) {
      // ---- 3-gate GEMM over all 13 jt; W tile staged per jt; own rows updated in place ----
      float dreg[8];
#pragma unroll
      for (int m = 0; m < 2; ++m)
#pragma unroll
        for (int r = 0; r < 4; ++r)
          dreg[m * 4 + r] = DECIN[wv * 32 + m * 16 + 4 * q + r];
#pragma unroll 1
      for (int jt = 0; jt < 13; ++jt) {
        __syncthreads();                            // BST free
        for (int i = wv; i < 21; i += 8) {
          int g = i / 7, p = i - g * 7;
          gload_lds16(Wbig + (g * 208 + jt * 16) * 224 + p * 512 + lane * 8,
                      BST + g * 3584 + p * 512);
        }
        __syncthreads();                            // staged
        floatx4 Cr[2] = {{0,0,0,0},{0,0,0,0}};
        floatx4 Cz[2] = {{0,0,0,0},{0,0,0,0}};
        floatx4 Cn[2] = {{0,0,0,0},{0,0,0,0}};
#pragma unroll
        for (int s = 0; s < 7; ++s) {
          half8 Br = lds_frag16(BST + c * 224 + s * 32 + q * 8);
          half8 Bz = lds_frag16(BST + 3584 + c * 224 + s * 32 + q * 8);
          half8 Bn = lds_frag16(BST + 7168 + c * 224 + s * 32 + q * 8);
#pragma unroll
          for (int m = 0; m < 2; ++m) {
            Cr[m] = MFMA16(A[m][s], Br, Cr[m]);
            Cz[m] = MFMA16(A[m][s], Bz, Cz[m]);
            Cn[m] = MFMA16(A[m][s], Bn, Cn[m]);
          }
        }
        int col = jt * 16 + c;
        float wr = wihc[col], wz = wihc[208 + col], wn = wihc[416 + col];
        float br = bsum[col], bz = bsum[208 + col], bnih = bsum[416 + col];
        float bnhh = bhhn[col];
        bool wm = col < 200;
#pragma unroll
        for (int m = 0; m < 2; ++m) {
          _Float16* hp = myH + (m * 16 + 4 * q) * 208 + col;
#pragma unroll
          for (int r = 0; r < 4; ++r) {
            float d  = dreg[m * 4 + r];
            float ho = (float)hp[r * 208];
            float rgate = sigm(Cr[m][r] + fmaf(d, wr, br));
            float zgate = sigm(Cz[m][r] + fmaf(d, wz, bz));
            float ngate = tanh_(fmaf(d, wn, bnih) + rgate * (Cn[m][r] + bnhh));
            float hv = fmaf(zgate, ho - ngate, ngate);
            if (wm) hp[r * 208] = (_Float16)hv;
          }
        }
      }
    }
  }
}

extern "C" void kernel_launch(void* const* d_in, const int* in_sizes, int n_in,
                              void* d_out, int out_size, void* d_ws, size_t ws_size,
                              hipStream_t stream) {
  const float* enc_in = (const float*)d_in[0];
  const float* enc_w1 = (const float*)d_in[1];
  const float* enc_b1 = (const float*)d_in[2];
  const float* enc_w2 = (const float*)d_in[3];
  const float* enc_b2 = (const float*)d_in[4];
  const float* enc_wl = (const float*)d_in[5];
  const float* enc_bl = (const float*)d_in[6];
  const float* w_ih   = (const float*)d_in[7];
  const float* w_hh   = (const float*)d_in[8];
  const float* b_ih   = (const float*)d_in[9];
  const float* b_hh   = (const float*)d_in[10];
  const float* dw1    = (const float*)d_in[11];
  const float* db1    = (const float*)d_in[12];
  const float* dw2    = (const float*)d_in[13];
  const float* db2    = (const float*)d_in[14];
  const float* dw3    = (const float*)d_in[15];
  const float* db3    = (const float*)d_in[16];
  unsigned char* ws = (unsigned char*)d_ws;
  float* out = (float*)d_out;

  prep_kernel<<<dim3(256), dim3(256), 0, stream>>>(
      enc_w1, enc_b1, enc_w2, enc_b2, enc_wl, enc_bl,
      w_ih, w_hh, b_ih, b_hh, dw1, db1, dw2, db2, dw3, db3, ws);
  fused_kernel<<<dim3(512), dim3(512), 0, stream>>>(enc_in, ws, out);
}